// Round 18
// baseline (715.000 us; speedup 1.0000x reference)
//
#include <hip/hip_runtime.h>

typedef short short8 __attribute__((ext_vector_type(8)));
typedef float f32x4 __attribute__((ext_vector_type(4)));

__device__ __forceinline__ unsigned short f2bu(float f) {
  unsigned u = __builtin_bit_cast(unsigned, f);
  u += 0x7fffu + ((u >> 16) & 1u);
  return (unsigned short)(u >> 16);
}

// truncating bf16 pack (1 VALU op) — for paths where bias cancels (softmax P / O)
__device__ __forceinline__ unsigned short f2bt(float f) {
  return (unsigned short)(__builtin_bit_cast(unsigned, f) >> 16);
}

__device__ __forceinline__ float b2f(unsigned short b) {
  unsigned u = (unsigned)b << 16;
  return __builtin_bit_cast(float, u);
}

__device__ __forceinline__ float gelu_t(float x) {
  float x3 = x * x * x;
  float t = tanhf(0.7978845608028654f * (x + 0.044715f * x3));
  return 0.5f * x * (1.f + t);
}

__device__ __forceinline__ void gload16(const void* g, void* l) {
  __builtin_amdgcn_global_load_lds(
      (const __attribute__((address_space(1))) void*)g,
      (__attribute__((address_space(3))) void*)l, 16, 0, 0);
}

// ---------------- small prep ----------------
__global__ __launch_bounds__(256) void prep_small(
    const float* __restrict__ vec, const float* __restrict__ sol_t,
    float* __restrict__ silu_vec, float* __restrict__ scales) {
  __shared__ float red[4];
  int t = threadIdx.x;
  float v = (t < 64) ? sol_t[t] : 0.f;
#pragma unroll
  for (int o = 32; o > 0; o >>= 1) v += __shfl_down(v, o);
  if ((t & 63) == 0) red[t >> 6] = v;
  __syncthreads();
  if (t == 0) {
    float m = (red[0] + red[1] + red[2] + red[3]) * (1.f / 64.f);
    m = fmaxf(m, 0.1f);
    const float sc = 0.08838834764831845f;   // 128^-0.5
    const float l2e = 1.4426950408889634f;   // scores computed in log2 domain
    scales[0] = sc * l2e;
    scales[1] = sc / m * l2e;
  }
  for (int k = t; k < 2048; k += 256) {
    float x = vec[k];
    silu_vec[k] = x / (1.f + expf(-x));
  }
}

__global__ __launch_bounds__(256) void mod_kernel(
    const float* __restrict__ S, const float* __restrict__ mw,
    const float* __restrict__ mb, float* __restrict__ modb) {
  int idx = blockIdx.x * 256 + threadIdx.x;  // 16*2048
  int h = idx >> 11, n = idx & 2047;
  int y = n >> 5, x = n & 31;
  float cy = (y + 0.5f) * 0.125f - 0.5f;
  float cx = (x + 0.5f) * 0.25f - 0.5f;
  int y0 = (int)floorf(cy); float fy = cy - (float)y0;
  int x0 = (int)floorf(cx); float fx = cx - (float)x0;
  int y0c = min(max(y0, 0), 7), y1c = min(max(y0 + 1, 0), 7);
  int x0c = min(max(x0, 0), 7), x1c = min(max(x0 + 1, 0), 7);
  float v = (1.f - fy) * ((1.f - fx) * S[y0c * 8 + x0c] + fx * S[y0c * 8 + x1c]) +
            fy * ((1.f - fx) * S[y1c * 8 + x0c] + fx * S[y1c * 8 + x1c]);
  float t = v * mw[h] + mb[h];
  t = fminf(fmaxf(t, -2.f), 2.f);
  modb[idx] = expf(t);
}

__global__ __launch_bounds__(256) void ada_gemv(
    const float* __restrict__ sv,
    const float* __restrict__ Wi, const float* __restrict__ bi,
    const float* __restrict__ Wt, const float* __restrict__ bt,
    float* __restrict__ ei, float* __restrict__ et) {
  __shared__ float red[4][64];
  const float* W = blockIdx.y ? Wt : Wi;
  const float* bb = blockIdx.y ? bt : bi;
  float* e = blockIdx.y ? et : ei;
  int jl = threadIdx.x & 63, ks = threadIdx.x >> 6;
  int j = blockIdx.x * 64 + jl;
  float acc = 0.f;
  int k0 = ks * 512;
#pragma unroll 4
  for (int k = 0; k < 512; ++k) acc += sv[k0 + k] * W[(size_t)(k0 + k) * 12288 + j];
  red[ks][jl] = acc;
  __syncthreads();
  if (ks == 0) e[j] = red[0][jl] + red[1][jl] + red[2][jl] + red[3][jl] + bb[j];
}

// ---------------- norm1: RMSNorm + adaLN modulate (txt+img merged) -> bf16 ----------
__global__ __launch_bounds__(256) void norm1_kernel(
    const float* __restrict__ txt, const float* __restrict__ img,
    const float* __restrict__ nw_t, const float* __restrict__ nw_i,
    const float* __restrict__ e_t, const float* __restrict__ e_i,
    unsigned short* __restrict__ out) {
  __shared__ float red[4];
  int r = blockIdx.x, t = threadIdx.x;
  bool ist = r < 512;
  const float* X = ist ? txt + (size_t)r * 2048 : img + (size_t)(r - 512) * 2048;
  const float* nw = ist ? nw_t : nw_i;
  const float* e = ist ? e_t : e_i;
  const float4* xr = reinterpret_cast<const float4*>(X);
  float4 v0 = xr[t * 2], v1 = xr[t * 2 + 1];
  float ss = v0.x * v0.x + v0.y * v0.y + v0.z * v0.z + v0.w * v0.w +
             v1.x * v1.x + v1.y * v1.y + v1.z * v1.z + v1.w * v1.w;
#pragma unroll
  for (int o = 32; o > 0; o >>= 1) ss += __shfl_down(ss, o);
  if ((t & 63) == 0) red[t >> 6] = ss;
  __syncthreads();
  float rinv = rsqrtf((red[0] + red[1] + red[2] + red[3]) * (1.f / 2048.f) + 1e-6f);
  int c0 = t * 8;
  float xv[8] = {v0.x, v0.y, v0.z, v0.w, v1.x, v1.y, v1.z, v1.w};
  short8 ov;
#pragma unroll
  for (int i = 0; i < 8; ++i) {
    int c = c0 + i;
    float y = xv[i] * rinv * nw[c] * (1.f + e[2048 + c]) + e[c];
    ov[i] = (short)f2bu(y);
  }
  *reinterpret_cast<short8*>(out + (size_t)r * 2048 + c0) = ov;
}

// ---------------- fused residual1 + RMSNorm2+mod ----------------
__global__ __launch_bounds__(256) void res1_rms(
    const float* __restrict__ txt, const float* __restrict__ img,
    const float* __restrict__ P0, const float* __restrict__ P1,
    const float* __restrict__ e_t, const float* __restrict__ e_i,
    const float* __restrict__ nw_t, const float* __restrict__ nw_i,
    float* __restrict__ out, unsigned short* __restrict__ actA) {
  __shared__ float red[4];
  int r = blockIdx.x, t = threadIdx.x;
  bool ist = r < 512;
  const float* X = ist ? txt + (size_t)r * 2048 : img + (size_t)(r - 512) * 2048;
  const float* e = ist ? e_t : e_i;
  const float* nw = ist ? nw_t : nw_i;
  int c0 = t * 8;
  const float* p0 = P0 + (size_t)r * 2048 + c0;
  const float* p1 = P1 + (size_t)r * 2048 + c0;
  float o[8];
  float ss = 0.f;
#pragma unroll
  for (int i = 0; i < 8; i += 4) {
    float4 x = *reinterpret_cast<const float4*>(X + c0 + i);
    float4 a = *reinterpret_cast<const float4*>(p0 + i);
    float4 b = *reinterpret_cast<const float4*>(p1 + i);
    float4 g = *reinterpret_cast<const float4*>(e + 4096 + c0 + i);
    o[i + 0] = x.x + g.x * (a.x + b.x);
    o[i + 1] = x.y + g.y * (a.y + b.y);
    o[i + 2] = x.z + g.z * (a.z + b.z);
    o[i + 3] = x.w + g.w * (a.w + b.w);
    ss += o[i] * o[i] + o[i + 1] * o[i + 1] + o[i + 2] * o[i + 2] + o[i + 3] * o[i + 3];
  }
  *reinterpret_cast<float4*>(out + (size_t)r * 2048 + c0) =
      make_float4(o[0], o[1], o[2], o[3]);
  *reinterpret_cast<float4*>(out + (size_t)r * 2048 + c0 + 4) =
      make_float4(o[4], o[5], o[6], o[7]);
#pragma unroll
  for (int of = 32; of > 0; of >>= 1) ss += __shfl_down(ss, of);
  if ((t & 63) == 0) red[t >> 6] = ss;
  __syncthreads();
  float rinv = rsqrtf((red[0] + red[1] + red[2] + red[3]) * (1.f / 2048.f) + 1e-6f);
  short8 ov;
#pragma unroll
  for (int i = 0; i < 8; ++i) {
    int c = c0 + i;
    float y = o[i] * rinv * nw[c] * (1.f + e[8192 + c]) + e[6144 + c];
    ov[i] = (short)f2bu(y);
  }
  *reinterpret_cast<short8*>(actA + (size_t)r * 2048 + c0) = ov;
}

// ---------------- residual2 (txt+img merged) ----------------
__global__ __launch_bounds__(256) void res2_kernel(
    const float* __restrict__ P0, const float* __restrict__ P1,
    const float* __restrict__ b_t, const float* __restrict__ b_i,
    const float* __restrict__ e_t, const float* __restrict__ e_i,
    float* __restrict__ out) {
  int r = blockIdx.x, t = threadIdx.x;
  bool ist = r < 512;
  const float* e = ist ? e_t : e_i;
  const float* bb = ist ? b_t : b_i;
  int c0 = t * 8;
  const float* p0 = P0 + (size_t)r * 2048 + c0;
  const float* p1 = P1 + (size_t)r * 2048 + c0;
  float* op = out + (size_t)r * 2048 + c0;
#pragma unroll
  for (int i = 0; i < 8; i += 4) {
    float4 a = *reinterpret_cast<const float4*>(p0 + i);
    float4 b = *reinterpret_cast<const float4*>(p1 + i);
    float4 g = *reinterpret_cast<const float4*>(e + 10240 + c0 + i);
    float4 bv = *reinterpret_cast<const float4*>(bb + c0 + i);
    float4 o = *reinterpret_cast<const float4*>(op + i);
    o.x += g.x * (a.x + b.x + bv.x);
    o.y += g.y * (a.y + b.y + bv.y);
    o.z += g.z * (a.z + b.z + bv.z);
    o.w += g.w * (a.w + b.w + bv.w);
    *reinterpret_cast<float4*>(op + i) = o;
  }
}

// ---------------- weight transpose+convert: f32 [K][N] -> bf16 [N][K] ----------------
__global__ __launch_bounds__(256) void transpose_w(
    const float* __restrict__ W, unsigned short* __restrict__ Bt, int K, int N) {
  __shared__ float tile[64][33];
  int n0 = blockIdx.x * 32, k0 = blockIdx.y * 64;
  int tid = threadIdx.x;
  int tx = tid & 31, ty = tid >> 5;
#pragma unroll
  for (int j = 0; j < 8; ++j)
    tile[ty + j * 8][tx] = W[(size_t)(k0 + ty + j * 8) * N + n0 + tx];
  __syncthreads();
  int n = tid >> 3, ks = (tid & 7) * 8;
  unsigned pk[4];
#pragma unroll
  for (int i = 0; i < 4; ++i) {
    float lo = tile[ks + 2 * i][n], hi = tile[ks + 2 * i + 1][n];
    pk[i] = (unsigned)f2bu(lo) | ((unsigned)f2bu(hi) << 16);
  }
  int4 ov = make_int4(pk[0], pk[1], pk[2], pk[3]);
  *reinterpret_cast<int4*>(Bt + (size_t)(n0 + n) * K + k0 + ks) = ov;
}

__global__ __launch_bounds__(256) void transpose_v(
    const unsigned short* __restrict__ V, unsigned short* __restrict__ Vt) {
  __shared__ unsigned short tile[32][33];
  int h = blockIdx.z;
  int s0 = blockIdx.x * 32, d0 = blockIdx.y * 32;
  int tx = threadIdx.x, ty = threadIdx.y;
  const unsigned short* src = V + (size_t)h * 2560 * 128;
  unsigned short* dst = Vt + (size_t)h * 128 * 2560;
#pragma unroll
  for (int j = 0; j < 32; j += 8)
    tile[ty + j][tx] = src[(size_t)(s0 + ty + j) * 128 + d0 + tx];
  __syncthreads();
#pragma unroll
  for (int j = 0; j < 32; j += 8)
    dst[(size_t)(d0 + ty + j) * 2560 + s0 + tx] = tile[tx][ty + j];
}

// ---------------- batched GEMM (txt rows 0..511, img rows 512..2559) ----------------
struct GemmP {
  const unsigned short *A, *Bt_t, *Bt_i;
  float* C;
  unsigned short* Cb;
  const float *bias_t, *bias_i;
  const float *rope, *modb;
  unsigned short *q_txt, *q_img, *k_cat, *v_cat;
  const float* scales;
  int Mb_t;
  int N, K, KS;
};

template <int EPI>
__global__ __launch_bounds__(256) void gemm2(GemmP p) {
  __shared__ __align__(16) char GRAW[65536];
  int4* sAb = reinterpret_cast<int4*>(GRAW);            // [2][1024] int4 (32KB)
  int4* sBb = reinterpret_cast<int4*>(GRAW + 32768);    // [2][1024] int4 (32KB)
  const int NB = gridDim.x, MBT = gridDim.y;
  int nwg = NB * MBT;
  int orig = blockIdx.y * NB + blockIdx.x;
  int qq = nwg >> 3, rr = nwg & 7, xcd = orig & 7, base = orig >> 3;
  int sw = (xcd < rr ? xcd * (qq + 1) : rr * (qq + 1) + (xcd - rr) * qq) + base;
  int bx = sw / MBT, by = sw % MBT;
  const bool is_t = by < p.Mb_t;
  const unsigned short* Bt = is_t ? p.Bt_t : p.Bt_i;
  const int m0 = by * 128, n0 = bx * 128;
  const int z = blockIdx.z;
  const int Kz = p.K / p.KS, kbeg = z * Kz, kend = kbeg + Kz;
  const int tid = threadIdx.x;
  const int w = tid >> 6, l = tid & 63, lr = l & 15, lg = l >> 4;
  const int wm = (w >> 1) * 64, wn = (w & 1) * 64;
  f32x4 acc[4][4] = {};
  const int4* Ag = reinterpret_cast<const int4*>(p.A);
  const int4* Bg = reinterpret_cast<const int4*>(Bt);
  const int K8 = p.K >> 3;
  int srow[4], sch[4];
#pragma unroll
  for (int i = 0; i < 4; ++i) {
    int s = i * 256 + tid;
    srow[i] = s >> 3;
    sch[i] = (s & 7) ^ (srow[i] & 7);
  }
  {
    int kc = kbeg >> 3;
#pragma unroll
    for (int i = 0; i < 4; ++i) {
      gload16(&Ag[(size_t)(m0 + srow[i]) * K8 + kc + sch[i]], &sAb[i * 256 + w * 64]);
      gload16(&Bg[(size_t)(n0 + srow[i]) * K8 + kc + sch[i]], &sBb[i * 256 + w * 64]);
    }
  }
  asm volatile("s_waitcnt vmcnt(0)" ::: "memory");
  __builtin_amdgcn_sched_barrier(0);
  __builtin_amdgcn_s_barrier();
  int cur = 0;
  for (int k0 = kbeg; k0 < kend; k0 += 64) {
    if (k0 + 64 < kend) {
      int kc = (k0 + 64) >> 3;
      int nb = (cur ^ 1) * 1024;
#pragma unroll
      for (int i = 0; i < 4; ++i) {
        gload16(&Ag[(size_t)(m0 + srow[i]) * K8 + kc + sch[i]], &sAb[nb + i * 256 + w * 64]);
        gload16(&Bg[(size_t)(n0 + srow[i]) * K8 + kc + sch[i]], &sBb[nb + i * 256 + w * 64]);
      }
      __builtin_amdgcn_sched_barrier(0);
    }
    const short8* pA = reinterpret_cast<const short8*>(sAb + cur * 1024);
    const short8* pB = reinterpret_cast<const short8*>(sBb + cur * 1024);
    __builtin_amdgcn_s_setprio(1);
#pragma unroll
    for (int kk = 0; kk < 2; ++kk) {
      short8 af[4], bf[4];
#pragma unroll
      for (int m = 0; m < 4; ++m) {
        int row = wm + m * 16 + lr;
        af[m] = pA[row * 8 + ((kk * 4 + lg) ^ (row & 7))];
      }
#pragma unroll
      for (int n = 0; n < 4; ++n) {
        int row = wn + n * 16 + lr;
        bf[n] = pB[row * 8 + ((kk * 4 + lg) ^ (row & 7))];
      }
#pragma unroll
      for (int m = 0; m < 4; ++m)
#pragma unroll
        for (int n = 0; n < 4; ++n)
          acc[m][n] = __builtin_amdgcn_mfma_f32_16x16x32_bf16(af[m], bf[n], acc[m][n], 0, 0, 0);
    }
    __builtin_amdgcn_s_setprio(0);
    asm volatile("s_waitcnt vmcnt(0)" ::: "memory");  // next tile landed
    __builtin_amdgcn_sched_barrier(0);
    __builtin_amdgcn_s_barrier();
    cur ^= 1;
  }
  if (EPI == 0) {
    float* C = p.C + (size_t)z * MBT * 128 * p.N;
#pragma unroll
    for (int m = 0; m < 4; ++m)
#pragma unroll
      for (int n = 0; n < 4; ++n)
#pragma unroll
        for (int j = 0; j < 4; ++j) {
          int r = m0 + wm + m * 16 + lg * 4 + j;
          int cc = n0 + wn + n * 16 + lr;
          C[(size_t)r * p.N + cc] = acc[m][n][j];
        }
  } else if (EPI == 1) {
    const float* bias = is_t ? p.bias_t : p.bias_i;
#pragma unroll
    for (int n = 0; n < 4; ++n) {
      int cc = n0 + wn + n * 16 + lr;
      float bv = bias[cc];
#pragma unroll
      for (int m = 0; m < 4; ++m)
#pragma unroll
        for (int j = 0; j < 4; ++j) {
          int r = m0 + wm + m * 16 + lg * 4 + j;
          p.Cb[(size_t)r * p.N + cc] = f2bu(gelu_t(acc[m][n][j] + bv));
        }
    }
  } else {
    unsigned short* osh = reinterpret_cast<unsigned short*>(GRAW);  // [128][136]
#pragma unroll
    for (int m = 0; m < 4; ++m)
#pragma unroll
      for (int n = 0; n < 4; ++n)
#pragma unroll
        for (int j = 0; j < 4; ++j) {
          int row = wm + m * 16 + lg * 4 + j;
          int col = wn + n * 16 + lr;
          osh[row * 136 + col] = f2bu(acc[m][n][j]);
        }
    __syncthreads();
    int sel = bx >> 4, h = bx & 15;
    int row = tid >> 1, d0 = (tid & 1) * 64;
    int r = m0 + row;
    const unsigned short* src = osh + row * 136 + d0;
    if (is_t) {
      if (sel == 0) {
        float qs = p.scales[0];
        unsigned short* dst = p.q_txt + ((size_t)h * 512 + r) * 128 + d0;
#pragma unroll
        for (int i = 0; i < 8; ++i) {
          short8 v = *reinterpret_cast<const short8*>(src + i * 8);
          short8 o;
#pragma unroll
          for (int t = 0; t < 8; ++t)
            o[t] = (short)f2bu(b2f((unsigned short)v[t]) * qs);
          *reinterpret_cast<short8*>(dst + i * 8) = o;
        }
      } else {
        unsigned short* dst =
            (sel == 1 ? p.k_cat : p.v_cat) + ((size_t)h * 2560 + r) * 128 + d0;
#pragma unroll
        for (int i = 0; i < 8; ++i)
          *reinterpret_cast<short8*>(dst + i * 8) =
              *reinterpret_cast<const short8*>(src + i * 8);
      }
    } else {
      int s = r - 512;
      if (sel == 2) {
        unsigned short* dst = p.v_cat + ((size_t)h * 2560 + r) * 128 + d0;
#pragma unroll
        for (int i = 0; i < 8; ++i)
          *reinterpret_cast<short8*>(dst + i * 8) =
              *reinterpret_cast<const short8*>(src + i * 8);
      } else {
        float mv = p.modb[h * 2048 + s];
        float qs = (sel == 0) ? p.scales[1] * mv : mv;
        const float2* rp = reinterpret_cast<const float2*>(p.rope + (size_t)s * 128 + d0);
        unsigned short* dst = (sel == 0)
            ? p.q_img + ((size_t)h * 2048 + s) * 128 + d0
            : p.k_cat + ((size_t)h * 2560 + r) * 128 + d0;
#pragma unroll
        for (int i = 0; i < 8; ++i) {
          short8 v = *reinterpret_cast<const short8*>(src + i * 8);
          short8 o;
#pragma unroll
          for (int t = 0; t < 4; ++t) {
            float2 cs = rp[i * 4 + t];
            float e = b2f((unsigned short)v[2 * t]);
            float od = b2f((unsigned short)v[2 * t + 1]);
            o[2 * t] = (short)f2bu((e * cs.x - od * cs.y) * qs);
            o[2 * t + 1] = (short)f2bu((od * cs.x + e * cs.y) * qs);
          }
          *reinterpret_cast<short8*>(dst + i * 8) = o;
        }
      }
    }
  }
}

// ---------------- split-KV flash attention (QBLK=64, z=4, phase-pipelined) ----------
__global__ __launch_bounds__(256, 4) void attn_kernel(
    const unsigned short* __restrict__ q_txt, const unsigned short* __restrict__ q_img,
    const unsigned short* __restrict__ Kc, const unsigned short* __restrict__ Vt,
    unsigned short* __restrict__ Op, float* __restrict__ ml) {
  __shared__ __align__(16) char RAW[40960];
  int4* sK = reinterpret_cast<int4*>(RAW);            // [64 kv][16 int4] 16KB
  int4* sV = reinterpret_cast<int4*>(RAW + 16384);    // [128 d][8 int4] 16KB
  int4* sP = reinterpret_cast<int4*>(RAW + 32768);    // [64 q][8 int4] 8KB
  unsigned short* osh = reinterpret_cast<unsigned short*>(RAW);  // overlay, stride 136
  const int tid = threadIdx.x, w = tid >> 6, l = tid & 63, lr = l & 15, lg = l >> 4;
  int flat = blockIdx.x + 40 * (blockIdx.y + 16 * blockIdx.z);  // [0,2560)
  int sw = (flat & 7) * 320 + (flat >> 3);
  const int bx = sw % 40;
  int hz = sw / 40;
  const int h = hz & 15, z = hz >> 4;
  const bool is_t = bx < 8;
  const int orow = is_t ? bx * 64 : 512 + (bx - 8) * 64;
  const unsigned short* Qp = is_t ? q_txt + ((size_t)h * 512 + bx * 64) * 128
                                  : q_img + ((size_t)h * 2048 + (bx - 8) * 64) * 128;
  short8 aq[4];
#pragma unroll
  for (int ds = 0; ds < 4; ++ds) {
    int row = w * 16 + lr;
    aq[ds] = *reinterpret_cast<const short8*>(Qp + (size_t)row * 128 + ds * 32 + lg * 8);
  }
  const int4* Kg = reinterpret_cast<const int4*>(Kc + (size_t)h * 2560 * 128);
  const int4* Vg = reinterpret_cast<const int4*>(Vt + (size_t)h * 128 * 2560);
  const short8* pK = reinterpret_cast<const short8*>(sK);
  const short8* pV = reinterpret_cast<const short8*>(sV);
  const short8* pP = reinterpret_cast<const short8*>(sP);
  unsigned short* sPb = reinterpret_cast<unsigned short*>(sP);
  int krow[4], kch[4], vrow[4], vch[4];
#pragma unroll
  for (int i = 0; i < 4; ++i) {
    int s = i * 256 + tid;
    krow[i] = s >> 4; kch[i] = (s & 15) ^ (krow[i] & 7);
    vrow[i] = s >> 3; vch[i] = (s & 7) ^ (vrow[i] & 7);
  }
  short8 ones8;
#pragma unroll
  for (int i = 0; i < 8; ++i) ones8[i] = (short)0x3F80;

  f32x4 oacc[8] = {};
  f32x4 oacc_l = {};
  float m_run[4];
#pragma unroll
  for (int j = 0; j < 4; ++j) m_run[j] = -1e30f;

  const int kbeg = z * 10, kend = kbeg + 10;
#pragma unroll
  for (int i = 0; i < 4; ++i)
    gload16(&Kg[(size_t)(kbeg * 64 + krow[i]) * 16 + kch[i]], &sK[i * 256 + w * 64]);
#pragma unroll
  for (int i = 0; i < 4; ++i)
    gload16(&Vg[(size_t)vrow[i] * 320 + kbeg * 8 + vch[i]], &sV[i * 256 + w * 64]);

  for (int kt = kbeg; kt < kend; ++kt) {
    asm volatile("s_waitcnt vmcnt(4)" ::: "memory");
    __builtin_amdgcn_sched_barrier(0);
    __builtin_amdgcn_s_barrier();
    f32x4 sacc[4] = {};
    __builtin_amdgcn_s_setprio(1);
#pragma unroll
    for (int ds = 0; ds < 4; ++ds) {
      short8 bk[4];
#pragma unroll
      for (int n = 0; n < 4; ++n) {
        int row = n * 16 + lr;
        bk[n] = pK[row * 16 + ((ds * 4 + lg) ^ (row & 7))];
      }
#pragma unroll
      for (int n = 0; n < 4; ++n)
        sacc[n] = __builtin_amdgcn_mfma_f32_16x16x32_bf16(aq[ds], bk[n], sacc[n], 0, 0, 0);
    }
    __builtin_amdgcn_s_setprio(0);
    __builtin_amdgcn_s_barrier();  // release sK
    if (kt + 1 < kend) {
#pragma unroll
      for (int i = 0; i < 4; ++i)
        gload16(&Kg[(size_t)((kt + 1) * 64 + krow[i]) * 16 + kch[i]], &sK[i * 256 + w * 64]);
    }
    float corr_[4];
    bool grow_any = false;
#pragma unroll
    for (int j = 0; j < 4; ++j) {
      float mx = fmaxf(fmaxf(sacc[0][j], sacc[1][j]), fmaxf(sacc[2][j], sacc[3][j]));
      mx = fmaxf(mx, __shfl_xor(mx, 1));
      mx = fmaxf(mx, __shfl_xor(mx, 2));
      mx = fmaxf(mx, __shfl_xor(mx, 4));
      mx = fmaxf(mx, __shfl_xor(mx, 8));
      bool grow = mx > m_run[j] + 11.0f;
      grow_any |= grow;
      float mn = grow ? mx : m_run[j];
      corr_[j] = grow ? exp2f(m_run[j] - mn) : 1.0f;  // transcendental only on grow
      m_run[j] = mn;
      int prow = w * 16 + lg * 4 + j;
#pragma unroll
      for (int n = 0; n < 4; ++n) {
        float pp = exp2f(sacc[n][j] - mn);
        int col = n * 16 + lr;
        // truncating pack: bias cancels in O = sum(p v)/sum(p)
        sPb[prow * 64 + (((col >> 3) ^ (prow & 7)) << 3) + (col & 7)] = f2bt(pp);
      }
    }
    if (__any(grow_any)) {
#pragma unroll
      for (int n = 0; n < 8; ++n)
#pragma unroll
        for (int j = 0; j < 4; ++j) oacc[n][j] *= corr_[j];
#pragma unroll
      for (int j = 0; j < 4; ++j) oacc_l[j] *= corr_[j];
    }
    if (kt + 1 < kend) {
      asm volatile("s_waitcnt vmcnt(4)" ::: "memory");
    } else {
      asm volatile("s_waitcnt vmcnt(0)" ::: "memory");
    }
    __builtin_amdgcn_sched_barrier(0);
    __builtin_amdgcn_s_barrier();
    __builtin_amdgcn_s_setprio(1);
#pragma unroll
    for (int kk = 0; kk < 2; ++kk) {
      short8 ap, bv[8];
      {
        int row = w * 16 + lr;
        ap = pP[row * 8 + ((kk * 4 + lg) ^ (row & 7))];
      }
#pragma unroll
      for (int n = 0; n < 8; ++n) {
        int row = n * 16 + lr;
        bv[n] = pV[row * 8 + ((kk * 4 + lg) ^ (row & 7))];
      }
#pragma unroll
      for (int n = 0; n < 8; ++n)
        oacc[n] = __builtin_amdgcn_mfma_f32_16x16x32_bf16(ap, bv[n], oacc[n], 0, 0, 0);
      oacc_l = __builtin_amdgcn_mfma_f32_16x16x32_bf16(ap, ones8, oacc_l, 0, 0, 0);
    }
    __builtin_amdgcn_s_setprio(0);
    __builtin_amdgcn_s_barrier();  // release sV
    if (kt + 1 < kend) {
#pragma unroll
      for (int i = 0; i < 4; ++i)
        gload16(&Vg[(size_t)vrow[i] * 320 + (kt + 1) * 8 + vch[i]], &sV[i * 256 + w * 64]);
    }
  }
  const size_t zbase = (size_t)z * 40960 + (size_t)h * 2560 + orow;
  __syncthreads();  // sK/sV/sP dead -> osh overlay
#pragma unroll
  for (int j = 0; j < 4; ++j) {
    int row = w * 16 + lg * 4 + j;
#pragma unroll
    for (int n = 0; n < 8; ++n)
      osh[row * 136 + n * 16 + lr] = f2bt(oacc[n][j]);
    if (lr == 0) {
      ml[(zbase + row) * 2] = m_run[j];
      ml[(zbase + row) * 2 + 1] = oacc_l[j];
    }
  }
  __syncthreads();
  {
    int row = tid >> 2, c0 = (tid & 3) * 32;
#pragma unroll
    for (int i = 0; i < 4; ++i)
      *reinterpret_cast<short8*>(Op + (zbase + row) * 128 + c0 + i * 8) =
          *reinterpret_cast<const short8*>(osh + row * 136 + c0 + i * 8);
  }
}

// merge 4 KV-chunk partials (log2-domain LSE combine) -> ao[r][h*128+d] bf16
__global__ __launch_bounds__(256) void attn_merge(
    const unsigned short* __restrict__ Op, const float* __restrict__ ml,
    unsigned short* __restrict__ ao) {
  int gid = blockIdx.x * 256 + threadIdx.x;  // 40960 rows * 32 threads
  int rid = gid >> 5, d0 = (gid & 31) * 4;
  int h = rid / 2560;
  int r = rid - h * 2560;
  float M = -1e30f;
#pragma unroll
  for (int z = 0; z < 4; ++z) M = fmaxf(M, ml[((size_t)z * 40960 + rid) * 2]);
  float L = 0.f, o0 = 0.f, o1 = 0.f, o2 = 0.f, o3 = 0.f;
#pragma unroll
  for (int z = 0; z < 4; ++z) {
    size_t sidx = (size_t)z * 40960 + rid;
    float mz = ml[sidx * 2], lz = ml[sidx * 2 + 1];
    float wgt = exp2f(mz - M);
    L += wgt * lz;
    ushort4 v = *reinterpret_cast<const ushort4*>(Op + sidx * 128 + d0);
    o0 += wgt * b2f(v.x); o1 += wgt * b2f(v.y);
    o2 += wgt * b2f(v.z); o3 += wgt * b2f(v.w);
  }
  float inv = 1.f / L;
  ushort4 ov;
  ov.x = f2bu(o0 * inv); ov.y = f2bu(o1 * inv);
  ov.z = f2bu(o2 * inv); ov.w = f2bu(o3 * inv);
  *reinterpret_cast<ushort4*>(ao + (size_t)r * 2048 + h * 128 + d0) = ov;
}

extern "C" void kernel_launch(void* const* d_in, const int* in_sizes, int n_in,
                              void* d_out, int out_size, void* d_ws, size_t ws_size,
                              hipStream_t stream) {
  (void)in_sizes; (void)n_in; (void)out_size; (void)ws_size;
  const float* txt = (const float*)d_in[0];
  const float* img = (const float*)d_in[1];
  const float* vec = (const float*)d_in[2];
  const float* rope = (const float*)d_in[3];
  const float* sol_t = (const float*)d_in[4];
  const float* sol_s = (const float*)d_in[5];
  const float* ada_img_w = (const float*)d_in[6];
  const float* ada_img_b = (const float*)d_in[7];
  const float* ada_img_nw = (const float*)d_in[8];
  const float* ada_txt_w = (const float*)d_in[9];
  const float* ada_txt_b = (const float*)d_in[10];
  const float* ada_txt_nw = (const float*)d_in[11];
  const float* txt_qkv_w = (const float*)d_in[12];
  const float* img_qkv_w = (const float*)d_in[13];
  const float* txt_out_w = (const float*)d_in[14];
  const float* img_out_w = (const float*)d_in[15];
  const float* mod_w = (const float*)d_in[16];
  const float* mod_b = (const float*)d_in[17];
  const float* img_n2_w = (const float*)d_in[18];
  const float* txt_n2_w = (const float*)d_in[19];
  const float* img_fc1_w = (const float*)d_in[20];
  const float* img_fc1_b = (const float*)d_in[21];
  const float* img_fc2_w = (const float*)d_in[22];
  const float* img_fc2_b = (const float*)d_in[23];
  const float* txt_fc1_w = (const float*)d_in[24];
  const float* txt_fc1_b = (const float*)d_in[25];
  const float* txt_fc2_w = (const float*)d_in[26];
  const float* txt_fc2_b = (const float*)d_in[27];
  float* out = (float*)d_out;
  char* ws = (char*)d_ws;

  const size_t MB = 1 << 20;
  float* silu_vec = (float*)(ws + 0);
  float* scales = (float*)(ws + 8192);
  float* modb = (float*)(ws + 16384);
  float* e_img = (float*)(ws + 147456);
  float* e_txt = (float*)(ws + 196608);
  unsigned short* wt0 = (unsigned short*)(ws + 1 * MB);    // 32MB txt weights
  unsigned short* wt1 = (unsigned short*)(ws + 33 * MB);   // 32MB img weights
  unsigned short* Opart = (unsigned short*)(ws + 1 * MB);  // overlays weights (dead then)
  float* mlbuf = (float*)(ws + 42 * MB);                   // 1.25MB
  unsigned short* actA = (unsigned short*)(ws + 65 * MB);  // [2560][2048] bf16, 10MB
  char* attn_base = ws + 75 * MB;                          // 50MB region
  unsigned short* q_txt = (unsigned short*)(attn_base);
  unsigned short* q_img = (unsigned short*)(attn_base + 2 * MB);
  unsigned short* k_cat = (unsigned short*)(attn_base + 10 * MB);
  unsigned short* v_cat = (unsigned short*)(attn_base + 20 * MB);
  unsigned short* vT = (unsigned short*)(attn_base + 30 * MB);
  unsigned short* ao = (unsigned short*)(attn_base + 40 * MB);
  unsigned short* actB = (unsigned short*)attn_base;  // [2560][8192] bf16 (MLP phase)
  float* Cbuf = (float*)(ws + 125 * MB);  // 2 partials x [2560][2048] f32 = 40MB
  const size_t PSTR = (size_t)2560 * 2048;

  prep_small<<<1, 256, 0, stream>>>(vec, sol_t, silu_vec, scales);
  mod_kernel<<<128, 256, 0, stream>>>(sol_s, mod_w, mod_b, modb);
  ada_gemv<<<dim3(192, 2), 256, 0, stream>>>(silu_vec, ada_img_w, ada_img_b,
                                             ada_txt_w, ada_txt_b, e_img, e_txt);
  norm1_kernel<<<2560, 256, 0, stream>>>(txt, img, ada_txt_nw, ada_img_nw,
                                         e_txt, e_img, actA);
  transpose_w<<<dim3(192, 32), 256, 0, stream>>>(txt_qkv_w, wt0, 2048, 6144);
  transpose_w<<<dim3(192, 32), 256, 0, stream>>>(img_qkv_w, wt1, 2048, 6144);
  {
    GemmP p = {actA, wt0, wt1, nullptr, nullptr, nullptr, nullptr,
               rope, modb, q_txt, q_img, k_cat, v_cat, scales, 4, 6144, 2048, 1};
    gemm2<2><<<dim3(48, 20, 1), 256, 0, stream>>>(p);
  }
  transpose_v<<<dim3(80, 4, 16), dim3(32, 8), 0, stream>>>(v_cat, vT);
  attn_kernel<<<dim3(40, 16, 4), 256, 0, stream>>>(q_txt, q_img, k_cat, vT, Opart, mlbuf);
  attn_merge<<<5120, 256, 0, stream>>>(Opart, mlbuf, ao);
  transpose_w<<<dim3(64, 32), 256, 0, stream>>>(txt_out_w, wt0, 2048, 2048);
  transpose_w<<<dim3(64, 32), 256, 0, stream>>>(img_out_w, wt1, 2048, 2048);
  {
    GemmP p = {ao, wt0, wt1, Cbuf, nullptr, nullptr, nullptr,
               nullptr, nullptr, nullptr, nullptr, nullptr, nullptr, nullptr, 4, 2048, 2048, 2};
    gemm2<0><<<dim3(16, 20, 2), 256, 0, stream>>>(p);
  }
  res1_rms<<<2560, 256, 0, stream>>>(txt, img, Cbuf, Cbuf + PSTR, e_txt, e_img,
                                     txt_n2_w, img_n2_w, out, actA);
  transpose_w<<<dim3(256, 32), 256, 0, stream>>>(txt_fc1_w, wt0, 2048, 8192);
  transpose_w<<<dim3(256, 32), 256, 0, stream>>>(img_fc1_w, wt1, 2048, 8192);
  {
    GemmP p = {actA, wt0, wt1, nullptr, actB, txt_fc1_b, img_fc1_b,
               nullptr, nullptr, nullptr, nullptr, nullptr, nullptr, nullptr, 4, 8192, 2048, 1};
    gemm2<1><<<dim3(64, 20, 1), 256, 0, stream>>>(p);
  }
  transpose_w<<<dim3(64, 128), 256, 0, stream>>>(txt_fc2_w, wt0, 8192, 2048);
  transpose_w<<<dim3(64, 128), 256, 0, stream>>>(img_fc2_w, wt1, 8192, 2048);
  {
    GemmP p = {actB, wt0, wt1, Cbuf, nullptr, nullptr, nullptr,
               nullptr, nullptr, nullptr, nullptr, nullptr, nullptr, nullptr, 4, 2048, 8192, 2};
    gemm2<0><<<dim3(16, 20, 2), 256, 0, stream>>>(p);
  }
  res2_kernel<<<2560, 256, 0, stream>>>(Cbuf, Cbuf + PSTR, txt_fc2_b, img_fc2_b,
                                        e_txt, e_img, out);
}

// Round 19
// 701.457 us; speedup vs baseline: 1.0193x; 1.0193x over previous
//
#include <hip/hip_runtime.h>

typedef short short8 __attribute__((ext_vector_type(8)));
typedef float f32x4 __attribute__((ext_vector_type(4)));

__device__ __forceinline__ unsigned short f2bu(float f) {
  unsigned u = __builtin_bit_cast(unsigned, f);
  u += 0x7fffu + ((u >> 16) & 1u);
  return (unsigned short)(u >> 16);
}

// truncating bf16 pack (1 VALU op) — for paths where bias cancels (softmax P / O)
__device__ __forceinline__ unsigned short f2bt(float f) {
  return (unsigned short)(__builtin_bit_cast(unsigned, f) >> 16);
}

__device__ __forceinline__ float b2f(unsigned short b) {
  unsigned u = (unsigned)b << 16;
  return __builtin_bit_cast(float, u);
}

__device__ __forceinline__ float gelu_t(float x) {
  float x3 = x * x * x;
  float t = tanhf(0.7978845608028654f * (x + 0.044715f * x3));
  return 0.5f * x * (1.f + t);
}

__device__ __forceinline__ void gload16(const void* g, void* l) {
  __builtin_amdgcn_global_load_lds(
      (const __attribute__((address_space(1))) void*)g,
      (__attribute__((address_space(3))) void*)l, 16, 0, 0);
}

// ---------------- small prep ----------------
__global__ __launch_bounds__(256) void prep_small(
    const float* __restrict__ vec, const float* __restrict__ sol_t,
    float* __restrict__ silu_vec, float* __restrict__ scales) {
  __shared__ float red[4];
  int t = threadIdx.x;
  float v = (t < 64) ? sol_t[t] : 0.f;
#pragma unroll
  for (int o = 32; o > 0; o >>= 1) v += __shfl_down(v, o);
  if ((t & 63) == 0) red[t >> 6] = v;
  __syncthreads();
  if (t == 0) {
    float m = (red[0] + red[1] + red[2] + red[3]) * (1.f / 64.f);
    m = fmaxf(m, 0.1f);
    const float sc = 0.08838834764831845f;   // 128^-0.5
    const float l2e = 1.4426950408889634f;   // scores computed in log2 domain
    scales[0] = sc * l2e;
    scales[1] = sc / m * l2e;
  }
  for (int k = t; k < 2048; k += 256) {
    float x = vec[k];
    silu_vec[k] = x / (1.f + expf(-x));
  }
}

__global__ __launch_bounds__(256) void mod_kernel(
    const float* __restrict__ S, const float* __restrict__ mw,
    const float* __restrict__ mb, float* __restrict__ modb) {
  int idx = blockIdx.x * 256 + threadIdx.x;  // 16*2048
  int h = idx >> 11, n = idx & 2047;
  int y = n >> 5, x = n & 31;
  float cy = (y + 0.5f) * 0.125f - 0.5f;
  float cx = (x + 0.5f) * 0.25f - 0.5f;
  int y0 = (int)floorf(cy); float fy = cy - (float)y0;
  int x0 = (int)floorf(cx); float fx = cx - (float)x0;
  int y0c = min(max(y0, 0), 7), y1c = min(max(y0 + 1, 0), 7);
  int x0c = min(max(x0, 0), 7), x1c = min(max(x0 + 1, 0), 7);
  float v = (1.f - fy) * ((1.f - fx) * S[y0c * 8 + x0c] + fx * S[y0c * 8 + x1c]) +
            fy * ((1.f - fx) * S[y1c * 8 + x0c] + fx * S[y1c * 8 + x1c]);
  float t = v * mw[h] + mb[h];
  t = fminf(fmaxf(t, -2.f), 2.f);
  modb[idx] = expf(t);
}

__global__ __launch_bounds__(256) void ada_gemv(
    const float* __restrict__ sv,
    const float* __restrict__ Wi, const float* __restrict__ bi,
    const float* __restrict__ Wt, const float* __restrict__ bt,
    float* __restrict__ ei, float* __restrict__ et) {
  __shared__ float red[4][64];
  const float* W = blockIdx.y ? Wt : Wi;
  const float* bb = blockIdx.y ? bt : bi;
  float* e = blockIdx.y ? et : ei;
  int jl = threadIdx.x & 63, ks = threadIdx.x >> 6;
  int j = blockIdx.x * 64 + jl;
  float acc = 0.f;
  int k0 = ks * 512;
#pragma unroll 4
  for (int k = 0; k < 512; ++k) acc += sv[k0 + k] * W[(size_t)(k0 + k) * 12288 + j];
  red[ks][jl] = acc;
  __syncthreads();
  if (ks == 0) e[j] = red[0][jl] + red[1][jl] + red[2][jl] + red[3][jl] + bb[j];
}

// ---------------- norm1: RMSNorm + adaLN modulate (txt+img merged) -> bf16 ----------
__global__ __launch_bounds__(256) void norm1_kernel(
    const float* __restrict__ txt, const float* __restrict__ img,
    const float* __restrict__ nw_t, const float* __restrict__ nw_i,
    const float* __restrict__ e_t, const float* __restrict__ e_i,
    unsigned short* __restrict__ out) {
  __shared__ float red[4];
  int r = blockIdx.x, t = threadIdx.x;
  bool ist = r < 512;
  const float* X = ist ? txt + (size_t)r * 2048 : img + (size_t)(r - 512) * 2048;
  const float* nw = ist ? nw_t : nw_i;
  const float* e = ist ? e_t : e_i;
  const float4* xr = reinterpret_cast<const float4*>(X);
  float4 v0 = xr[t * 2], v1 = xr[t * 2 + 1];
  float ss = v0.x * v0.x + v0.y * v0.y + v0.z * v0.z + v0.w * v0.w +
             v1.x * v1.x + v1.y * v1.y + v1.z * v1.z + v1.w * v1.w;
#pragma unroll
  for (int o = 32; o > 0; o >>= 1) ss += __shfl_down(ss, o);
  if ((t & 63) == 0) red[t >> 6] = ss;
  __syncthreads();
  float rinv = rsqrtf((red[0] + red[1] + red[2] + red[3]) * (1.f / 2048.f) + 1e-6f);
  int c0 = t * 8;
  float xv[8] = {v0.x, v0.y, v0.z, v0.w, v1.x, v1.y, v1.z, v1.w};
  short8 ov;
#pragma unroll
  for (int i = 0; i < 8; ++i) {
    int c = c0 + i;
    float y = xv[i] * rinv * nw[c] * (1.f + e[2048 + c]) + e[c];
    ov[i] = (short)f2bu(y);
  }
  *reinterpret_cast<short8*>(out + (size_t)r * 2048 + c0) = ov;
}

// ---------------- fused residual1 + RMSNorm2+mod (single partial) ----------------
__global__ __launch_bounds__(256) void res1_rms(
    const float* __restrict__ txt, const float* __restrict__ img,
    const float* __restrict__ P0,
    const float* __restrict__ e_t, const float* __restrict__ e_i,
    const float* __restrict__ nw_t, const float* __restrict__ nw_i,
    float* __restrict__ out, unsigned short* __restrict__ actA) {
  __shared__ float red[4];
  int r = blockIdx.x, t = threadIdx.x;
  bool ist = r < 512;
  const float* X = ist ? txt + (size_t)r * 2048 : img + (size_t)(r - 512) * 2048;
  const float* e = ist ? e_t : e_i;
  const float* nw = ist ? nw_t : nw_i;
  int c0 = t * 8;
  const float* p0 = P0 + (size_t)r * 2048 + c0;
  float o[8];
  float ss = 0.f;
#pragma unroll
  for (int i = 0; i < 8; i += 4) {
    float4 x = *reinterpret_cast<const float4*>(X + c0 + i);
    float4 a = *reinterpret_cast<const float4*>(p0 + i);
    float4 g = *reinterpret_cast<const float4*>(e + 4096 + c0 + i);
    o[i + 0] = x.x + g.x * a.x;
    o[i + 1] = x.y + g.y * a.y;
    o[i + 2] = x.z + g.z * a.z;
    o[i + 3] = x.w + g.w * a.w;
    ss += o[i] * o[i] + o[i + 1] * o[i + 1] + o[i + 2] * o[i + 2] + o[i + 3] * o[i + 3];
  }
  *reinterpret_cast<float4*>(out + (size_t)r * 2048 + c0) =
      make_float4(o[0], o[1], o[2], o[3]);
  *reinterpret_cast<float4*>(out + (size_t)r * 2048 + c0 + 4) =
      make_float4(o[4], o[5], o[6], o[7]);
#pragma unroll
  for (int of = 32; of > 0; of >>= 1) ss += __shfl_down(ss, of);
  if ((t & 63) == 0) red[t >> 6] = ss;
  __syncthreads();
  float rinv = rsqrtf((red[0] + red[1] + red[2] + red[3]) * (1.f / 2048.f) + 1e-6f);
  short8 ov;
#pragma unroll
  for (int i = 0; i < 8; ++i) {
    int c = c0 + i;
    float y = o[i] * rinv * nw[c] * (1.f + e[8192 + c]) + e[6144 + c];
    ov[i] = (short)f2bu(y);
  }
  *reinterpret_cast<short8*>(actA + (size_t)r * 2048 + c0) = ov;
}

// ---------------- weight transpose+convert: f32 [K][N] -> bf16 [N][K] ----------------
__global__ __launch_bounds__(256) void transpose_w(
    const float* __restrict__ W, unsigned short* __restrict__ Bt, int K, int N) {
  __shared__ float tile[64][33];
  int n0 = blockIdx.x * 32, k0 = blockIdx.y * 64;
  int tid = threadIdx.x;
  int tx = tid & 31, ty = tid >> 5;
#pragma unroll
  for (int j = 0; j < 8; ++j)
    tile[ty + j * 8][tx] = W[(size_t)(k0 + ty + j * 8) * N + n0 + tx];
  __syncthreads();
  int n = tid >> 3, ks = (tid & 7) * 8;
  unsigned pk[4];
#pragma unroll
  for (int i = 0; i < 4; ++i) {
    float lo = tile[ks + 2 * i][n], hi = tile[ks + 2 * i + 1][n];
    pk[i] = (unsigned)f2bu(lo) | ((unsigned)f2bu(hi) << 16);
  }
  int4 ov = make_int4(pk[0], pk[1], pk[2], pk[3]);
  *reinterpret_cast<int4*>(Bt + (size_t)(n0 + n) * K + k0 + ks) = ov;
}

__global__ __launch_bounds__(256) void transpose_v(
    const unsigned short* __restrict__ V, unsigned short* __restrict__ Vt) {
  __shared__ unsigned short tile[32][33];
  int h = blockIdx.z;
  int s0 = blockIdx.x * 32, d0 = blockIdx.y * 32;
  int tx = threadIdx.x, ty = threadIdx.y;
  const unsigned short* src = V + (size_t)h * 2560 * 128;
  unsigned short* dst = Vt + (size_t)h * 128 * 2560;
#pragma unroll
  for (int j = 0; j < 32; j += 8)
    tile[ty + j][tx] = src[(size_t)(s0 + ty + j) * 128 + d0 + tx];
  __syncthreads();
#pragma unroll
  for (int j = 0; j < 32; j += 8)
    dst[(size_t)(d0 + ty + j) * 2560 + s0 + tx] = tile[tx][ty + j];
}

// ---------------- batched GEMM (txt rows 0..511, img rows 512..2559) ----------------
// EPI 0: f32 store. EPI 1: bf16 gelu(acc+bias). EPI 2: qkv scatter. EPI 3: fused res2.
struct GemmP {
  const unsigned short *A, *Bt_t, *Bt_i;
  float* C;            // EPI0: partial base; EPI3: 'out' (RMW)
  unsigned short* Cb;
  const float *bias_t, *bias_i;
  const float *rope, *modb;
  unsigned short *q_txt, *q_img, *k_cat, *v_cat;
  const float* scales;
  const float *ga_t, *ga_i;  // EPI3 gate arrays (e_txt, e_img)
  int Mb_t;
  int N, K, KS;
};

template <int EPI>
__global__ __launch_bounds__(256) void gemm2(GemmP p) {
  __shared__ __align__(16) char GRAW[65536];
  int4* sAb = reinterpret_cast<int4*>(GRAW);            // [2][1024] int4 (32KB)
  int4* sBb = reinterpret_cast<int4*>(GRAW + 32768);    // [2][1024] int4 (32KB)
  const int NB = gridDim.x, MBT = gridDim.y;
  int nwg = NB * MBT;
  int orig = blockIdx.y * NB + blockIdx.x;
  int qq = nwg >> 3, rr = nwg & 7, xcd = orig & 7, base = orig >> 3;
  int sw = (xcd < rr ? xcd * (qq + 1) : rr * (qq + 1) + (xcd - rr) * qq) + base;
  int bx = sw / MBT, by = sw % MBT;
  const bool is_t = by < p.Mb_t;
  const unsigned short* Bt = is_t ? p.Bt_t : p.Bt_i;
  const int m0 = by * 128, n0 = bx * 128;
  const int z = blockIdx.z;
  const int Kz = p.K / p.KS, kbeg = z * Kz, kend = kbeg + Kz;
  const int tid = threadIdx.x;
  const int w = tid >> 6, l = tid & 63, lr = l & 15, lg = l >> 4;
  const int wm = (w >> 1) * 64, wn = (w & 1) * 64;
  f32x4 acc[4][4] = {};
  const int4* Ag = reinterpret_cast<const int4*>(p.A);
  const int4* Bg = reinterpret_cast<const int4*>(Bt);
  const int K8 = p.K >> 3;
  int srow[4], sch[4];
#pragma unroll
  for (int i = 0; i < 4; ++i) {
    int s = i * 256 + tid;
    srow[i] = s >> 3;
    sch[i] = (s & 7) ^ (srow[i] & 7);
  }
  {
    int kc = kbeg >> 3;
#pragma unroll
    for (int i = 0; i < 4; ++i) {
      gload16(&Ag[(size_t)(m0 + srow[i]) * K8 + kc + sch[i]], &sAb[i * 256 + w * 64]);
      gload16(&Bg[(size_t)(n0 + srow[i]) * K8 + kc + sch[i]], &sBb[i * 256 + w * 64]);
    }
  }
  asm volatile("s_waitcnt vmcnt(0)" ::: "memory");
  __builtin_amdgcn_sched_barrier(0);
  __builtin_amdgcn_s_barrier();
  int cur = 0;
  for (int k0 = kbeg; k0 < kend; k0 += 64) {
    if (k0 + 64 < kend) {
      int kc = (k0 + 64) >> 3;
      int nb = (cur ^ 1) * 1024;
#pragma unroll
      for (int i = 0; i < 4; ++i) {
        gload16(&Ag[(size_t)(m0 + srow[i]) * K8 + kc + sch[i]], &sAb[nb + i * 256 + w * 64]);
        gload16(&Bg[(size_t)(n0 + srow[i]) * K8 + kc + sch[i]], &sBb[nb + i * 256 + w * 64]);
      }
      __builtin_amdgcn_sched_barrier(0);
    }
    const short8* pA = reinterpret_cast<const short8*>(sAb + cur * 1024);
    const short8* pB = reinterpret_cast<const short8*>(sBb + cur * 1024);
    __builtin_amdgcn_s_setprio(1);
#pragma unroll
    for (int kk = 0; kk < 2; ++kk) {
      short8 af[4], bf[4];
#pragma unroll
      for (int m = 0; m < 4; ++m) {
        int row = wm + m * 16 + lr;
        af[m] = pA[row * 8 + ((kk * 4 + lg) ^ (row & 7))];
      }
#pragma unroll
      for (int n = 0; n < 4; ++n) {
        int row = wn + n * 16 + lr;
        bf[n] = pB[row * 8 + ((kk * 4 + lg) ^ (row & 7))];
      }
#pragma unroll
      for (int m = 0; m < 4; ++m)
#pragma unroll
        for (int n = 0; n < 4; ++n)
          acc[m][n] = __builtin_amdgcn_mfma_f32_16x16x32_bf16(af[m], bf[n], acc[m][n], 0, 0, 0);
    }
    __builtin_amdgcn_s_setprio(0);
    asm volatile("s_waitcnt vmcnt(0)" ::: "memory");  // next tile landed
    __builtin_amdgcn_sched_barrier(0);
    __builtin_amdgcn_s_barrier();
    cur ^= 1;
  }
  if (EPI == 0) {
    float* C = p.C + (size_t)z * MBT * 128 * p.N;
#pragma unroll
    for (int m = 0; m < 4; ++m)
#pragma unroll
      for (int n = 0; n < 4; ++n)
#pragma unroll
        for (int j = 0; j < 4; ++j) {
          int r = m0 + wm + m * 16 + lg * 4 + j;
          int cc = n0 + wn + n * 16 + lr;
          C[(size_t)r * p.N + cc] = acc[m][n][j];
        }
  } else if (EPI == 1) {
    const float* bias = is_t ? p.bias_t : p.bias_i;
#pragma unroll
    for (int n = 0; n < 4; ++n) {
      int cc = n0 + wn + n * 16 + lr;
      float bv = bias[cc];
#pragma unroll
      for (int m = 0; m < 4; ++m)
#pragma unroll
        for (int j = 0; j < 4; ++j) {
          int r = m0 + wm + m * 16 + lg * 4 + j;
          p.Cb[(size_t)r * p.N + cc] = f2bu(gelu_t(acc[m][n][j] + bv));
        }
    }
  } else if (EPI == 3) {
    // fused residual2: out += g*(acc+bias), staged through LDS bf16, coalesced RMW
    unsigned short* osh = reinterpret_cast<unsigned short*>(GRAW);  // [128][136]
#pragma unroll
    for (int m = 0; m < 4; ++m)
#pragma unroll
      for (int n = 0; n < 4; ++n)
#pragma unroll
        for (int j = 0; j < 4; ++j) {
          int row = wm + m * 16 + lg * 4 + j;
          int col = wn + n * 16 + lr;
          osh[row * 136 + col] = f2bu(acc[m][n][j]);
        }
    __syncthreads();
    const float* gat = (is_t ? p.ga_t : p.ga_i) + 10240;
    const float* bias = is_t ? p.bias_t : p.bias_i;
    int row = tid >> 1, d0 = (tid & 1) * 64;
    int r = m0 + row;
    const unsigned short* src = osh + row * 136 + d0;
    float* op = p.C + (size_t)r * p.N + n0 + d0;
#pragma unroll
    for (int i = 0; i < 16; ++i) {
      float4 o = *reinterpret_cast<const float4*>(op + i * 4);
      float4 g = *reinterpret_cast<const float4*>(gat + n0 + d0 + i * 4);
      float4 bv = *reinterpret_cast<const float4*>(bias + n0 + d0 + i * 4);
      o.x += g.x * (b2f(src[i * 4 + 0]) + bv.x);
      o.y += g.y * (b2f(src[i * 4 + 1]) + bv.y);
      o.z += g.z * (b2f(src[i * 4 + 2]) + bv.z);
      o.w += g.w * (b2f(src[i * 4 + 3]) + bv.w);
      *reinterpret_cast<float4*>(op + i * 4) = o;
    }
  } else {
    unsigned short* osh = reinterpret_cast<unsigned short*>(GRAW);  // [128][136]
#pragma unroll
    for (int m = 0; m < 4; ++m)
#pragma unroll
      for (int n = 0; n < 4; ++n)
#pragma unroll
        for (int j = 0; j < 4; ++j) {
          int row = wm + m * 16 + lg * 4 + j;
          int col = wn + n * 16 + lr;
          osh[row * 136 + col] = f2bu(acc[m][n][j]);
        }
    __syncthreads();
    int sel = bx >> 4, h = bx & 15;
    int row = tid >> 1, d0 = (tid & 1) * 64;
    int r = m0 + row;
    const unsigned short* src = osh + row * 136 + d0;
    if (is_t) {
      if (sel == 0) {
        float qs = p.scales[0];
        unsigned short* dst = p.q_txt + ((size_t)h * 512 + r) * 128 + d0;
#pragma unroll
        for (int i = 0; i < 8; ++i) {
          short8 v = *reinterpret_cast<const short8*>(src + i * 8);
          short8 o;
#pragma unroll
          for (int t = 0; t < 8; ++t)
            o[t] = (short)f2bu(b2f((unsigned short)v[t]) * qs);
          *reinterpret_cast<short8*>(dst + i * 8) = o;
        }
      } else {
        unsigned short* dst =
            (sel == 1 ? p.k_cat : p.v_cat) + ((size_t)h * 2560 + r) * 128 + d0;
#pragma unroll
        for (int i = 0; i < 8; ++i)
          *reinterpret_cast<short8*>(dst + i * 8) =
              *reinterpret_cast<const short8*>(src + i * 8);
      }
    } else {
      int s = r - 512;
      if (sel == 2) {
        unsigned short* dst = p.v_cat + ((size_t)h * 2560 + r) * 128 + d0;
#pragma unroll
        for (int i = 0; i < 8; ++i)
          *reinterpret_cast<short8*>(dst + i * 8) =
              *reinterpret_cast<const short8*>(src + i * 8);
      } else {
        float mv = p.modb[h * 2048 + s];
        float qs = (sel == 0) ? p.scales[1] * mv : mv;
        const float2* rp = reinterpret_cast<const float2*>(p.rope + (size_t)s * 128 + d0);
        unsigned short* dst = (sel == 0)
            ? p.q_img + ((size_t)h * 2048 + s) * 128 + d0
            : p.k_cat + ((size_t)h * 2560 + r) * 128 + d0;
#pragma unroll
        for (int i = 0; i < 8; ++i) {
          short8 v = *reinterpret_cast<const short8*>(src + i * 8);
          short8 o;
#pragma unroll
          for (int t = 0; t < 4; ++t) {
            float2 cs = rp[i * 4 + t];
            float e = b2f((unsigned short)v[2 * t]);
            float od = b2f((unsigned short)v[2 * t + 1]);
            o[2 * t] = (short)f2bu((e * cs.x - od * cs.y) * qs);
            o[2 * t + 1] = (short)f2bu((od * cs.x + e * cs.y) * qs);
          }
          *reinterpret_cast<short8*>(dst + i * 8) = o;
        }
      }
    }
  }
}

// ---------------- split-KV flash attention (QBLK=64, z=4, phase-pipelined) ----------
__global__ __launch_bounds__(256, 4) void attn_kernel(
    const unsigned short* __restrict__ q_txt, const unsigned short* __restrict__ q_img,
    const unsigned short* __restrict__ Kc, const unsigned short* __restrict__ Vt,
    unsigned short* __restrict__ Op, float* __restrict__ ml) {
  __shared__ __align__(16) char RAW[40960];
  int4* sK = reinterpret_cast<int4*>(RAW);            // [64 kv][16 int4] 16KB
  int4* sV = reinterpret_cast<int4*>(RAW + 16384);    // [128 d][8 int4] 16KB
  int4* sP = reinterpret_cast<int4*>(RAW + 32768);    // [64 q][8 int4] 8KB
  unsigned short* osh = reinterpret_cast<unsigned short*>(RAW);  // overlay, stride 136
  const int tid = threadIdx.x, w = tid >> 6, l = tid & 63, lr = l & 15, lg = l >> 4;
  int flat = blockIdx.x + 40 * (blockIdx.y + 16 * blockIdx.z);  // [0,2560)
  int sw = (flat & 7) * 320 + (flat >> 3);
  const int bx = sw % 40;
  int hz = sw / 40;
  const int h = hz & 15, z = hz >> 4;
  const bool is_t = bx < 8;
  const int orow = is_t ? bx * 64 : 512 + (bx - 8) * 64;
  const unsigned short* Qp = is_t ? q_txt + ((size_t)h * 512 + bx * 64) * 128
                                  : q_img + ((size_t)h * 2048 + (bx - 8) * 64) * 128;
  short8 aq[4];
#pragma unroll
  for (int ds = 0; ds < 4; ++ds) {
    int row = w * 16 + lr;
    aq[ds] = *reinterpret_cast<const short8*>(Qp + (size_t)row * 128 + ds * 32 + lg * 8);
  }
  const int4* Kg = reinterpret_cast<const int4*>(Kc + (size_t)h * 2560 * 128);
  const int4* Vg = reinterpret_cast<const int4*>(Vt + (size_t)h * 128 * 2560);
  const short8* pK = reinterpret_cast<const short8*>(sK);
  const short8* pV = reinterpret_cast<const short8*>(sV);
  const short8* pP = reinterpret_cast<const short8*>(sP);
  unsigned short* sPb = reinterpret_cast<unsigned short*>(sP);
  int krow[4], kch[4], vrow[4], vch[4];
#pragma unroll
  for (int i = 0; i < 4; ++i) {
    int s = i * 256 + tid;
    krow[i] = s >> 4; kch[i] = (s & 15) ^ (krow[i] & 7);
    vrow[i] = s >> 3; vch[i] = (s & 7) ^ (vrow[i] & 7);
  }
  short8 ones8;
#pragma unroll
  for (int i = 0; i < 8; ++i) ones8[i] = (short)0x3F80;

  f32x4 oacc[8] = {};
  f32x4 oacc_l = {};
  float m_run[4];
#pragma unroll
  for (int j = 0; j < 4; ++j) m_run[j] = -1e30f;

  const int kbeg = z * 10, kend = kbeg + 10;
#pragma unroll
  for (int i = 0; i < 4; ++i)
    gload16(&Kg[(size_t)(kbeg * 64 + krow[i]) * 16 + kch[i]], &sK[i * 256 + w * 64]);
#pragma unroll
  for (int i = 0; i < 4; ++i)
    gload16(&Vg[(size_t)vrow[i] * 320 + kbeg * 8 + vch[i]], &sV[i * 256 + w * 64]);

  for (int kt = kbeg; kt < kend; ++kt) {
    asm volatile("s_waitcnt vmcnt(4)" ::: "memory");
    __builtin_amdgcn_sched_barrier(0);
    __builtin_amdgcn_s_barrier();
    f32x4 sacc[4] = {};
    __builtin_amdgcn_s_setprio(1);
#pragma unroll
    for (int ds = 0; ds < 4; ++ds) {
      short8 bk[4];
#pragma unroll
      for (int n = 0; n < 4; ++n) {
        int row = n * 16 + lr;
        bk[n] = pK[row * 16 + ((ds * 4 + lg) ^ (row & 7))];
      }
#pragma unroll
      for (int n = 0; n < 4; ++n)
        sacc[n] = __builtin_amdgcn_mfma_f32_16x16x32_bf16(aq[ds], bk[n], sacc[n], 0, 0, 0);
    }
    __builtin_amdgcn_s_setprio(0);
    __builtin_amdgcn_s_barrier();  // release sK
    if (kt + 1 < kend) {
#pragma unroll
      for (int i = 0; i < 4; ++i)
        gload16(&Kg[(size_t)((kt + 1) * 64 + krow[i]) * 16 + kch[i]], &sK[i * 256 + w * 64]);
    }
    float corr_[4];
    bool grow_any = false;
#pragma unroll
    for (int j = 0; j < 4; ++j) {
      float mx = fmaxf(fmaxf(sacc[0][j], sacc[1][j]), fmaxf(sacc[2][j], sacc[3][j]));
      mx = fmaxf(mx, __shfl_xor(mx, 1));
      mx = fmaxf(mx, __shfl_xor(mx, 2));
      mx = fmaxf(mx, __shfl_xor(mx, 4));
      mx = fmaxf(mx, __shfl_xor(mx, 8));
      bool grow = mx > m_run[j] + 11.0f;
      grow_any |= grow;
      float mn = grow ? mx : m_run[j];
      corr_[j] = grow ? exp2f(m_run[j] - mn) : 1.0f;
      m_run[j] = mn;
      int prow = w * 16 + lg * 4 + j;
#pragma unroll
      for (int n = 0; n < 4; ++n) {
        float pp = exp2f(sacc[n][j] - mn);
        int col = n * 16 + lr;
        sPb[prow * 64 + (((col >> 3) ^ (prow & 7)) << 3) + (col & 7)] = f2bt(pp);
      }
    }
    if (__any(grow_any)) {
#pragma unroll
      for (int n = 0; n < 8; ++n)
#pragma unroll
        for (int j = 0; j < 4; ++j) oacc[n][j] *= corr_[j];
#pragma unroll
      for (int j = 0; j < 4; ++j) oacc_l[j] *= corr_[j];
    }
    if (kt + 1 < kend) {
      asm volatile("s_waitcnt vmcnt(4)" ::: "memory");
    } else {
      asm volatile("s_waitcnt vmcnt(0)" ::: "memory");
    }
    __builtin_amdgcn_sched_barrier(0);
    __builtin_amdgcn_s_barrier();
    __builtin_amdgcn_s_setprio(1);
#pragma unroll
    for (int kk = 0; kk < 2; ++kk) {
      short8 ap, bv[8];
      {
        int row = w * 16 + lr;
        ap = pP[row * 8 + ((kk * 4 + lg) ^ (row & 7))];
      }
#pragma unroll
      for (int n = 0; n < 8; ++n) {
        int row = n * 16 + lr;
        bv[n] = pV[row * 8 + ((kk * 4 + lg) ^ (row & 7))];
      }
#pragma unroll
      for (int n = 0; n < 8; ++n)
        oacc[n] = __builtin_amdgcn_mfma_f32_16x16x32_bf16(ap, bv[n], oacc[n], 0, 0, 0);
      oacc_l = __builtin_amdgcn_mfma_f32_16x16x32_bf16(ap, ones8, oacc_l, 0, 0, 0);
    }
    __builtin_amdgcn_s_setprio(0);
    __builtin_amdgcn_s_barrier();  // release sV
    if (kt + 1 < kend) {
#pragma unroll
      for (int i = 0; i < 4; ++i)
        gload16(&Vg[(size_t)vrow[i] * 320 + (kt + 1) * 8 + vch[i]], &sV[i * 256 + w * 64]);
    }
  }
  const size_t zbase = (size_t)z * 40960 + (size_t)h * 2560 + orow;
  __syncthreads();  // sK/sV/sP dead -> osh overlay
#pragma unroll
  for (int j = 0; j < 4; ++j) {
    int row = w * 16 + lg * 4 + j;
#pragma unroll
    for (int n = 0; n < 8; ++n)
      osh[row * 136 + n * 16 + lr] = f2bt(oacc[n][j]);
    if (lr == 0) {
      ml[(zbase + row) * 2] = m_run[j];
      ml[(zbase + row) * 2 + 1] = oacc_l[j];
    }
  }
  __syncthreads();
  {
    int row = tid >> 2, c0 = (tid & 3) * 32;
#pragma unroll
    for (int i = 0; i < 4; ++i)
      *reinterpret_cast<short8*>(Op + (zbase + row) * 128 + c0 + i * 8) =
          *reinterpret_cast<const short8*>(osh + row * 136 + c0 + i * 8);
  }
}

// merge 4 KV-chunk partials (log2-domain LSE combine) -> ao[r][h*128+d] bf16
__global__ __launch_bounds__(256) void attn_merge(
    const unsigned short* __restrict__ Op, const float* __restrict__ ml,
    unsigned short* __restrict__ ao) {
  int gid = blockIdx.x * 256 + threadIdx.x;  // 40960 rows * 32 threads
  int rid = gid >> 5, d0 = (gid & 31) * 4;
  int h = rid / 2560;
  int r = rid - h * 2560;
  float M = -1e30f;
#pragma unroll
  for (int z = 0; z < 4; ++z) M = fmaxf(M, ml[((size_t)z * 40960 + rid) * 2]);
  float L = 0.f, o0 = 0.f, o1 = 0.f, o2 = 0.f, o3 = 0.f;
#pragma unroll
  for (int z = 0; z < 4; ++z) {
    size_t sidx = (size_t)z * 40960 + rid;
    float mz = ml[sidx * 2], lz = ml[sidx * 2 + 1];
    float wgt = exp2f(mz - M);
    L += wgt * lz;
    ushort4 v = *reinterpret_cast<const ushort4*>(Op + sidx * 128 + d0);
    o0 += wgt * b2f(v.x); o1 += wgt * b2f(v.y);
    o2 += wgt * b2f(v.z); o3 += wgt * b2f(v.w);
  }
  float inv = 1.f / L;
  ushort4 ov;
  ov.x = f2bu(o0 * inv); ov.y = f2bu(o1 * inv);
  ov.z = f2bu(o2 * inv); ov.w = f2bu(o3 * inv);
  *reinterpret_cast<ushort4*>(ao + (size_t)r * 2048 + h * 128 + d0) = ov;
}

extern "C" void kernel_launch(void* const* d_in, const int* in_sizes, int n_in,
                              void* d_out, int out_size, void* d_ws, size_t ws_size,
                              hipStream_t stream) {
  (void)in_sizes; (void)n_in; (void)out_size; (void)ws_size;
  const float* txt = (const float*)d_in[0];
  const float* img = (const float*)d_in[1];
  const float* vec = (const float*)d_in[2];
  const float* rope = (const float*)d_in[3];
  const float* sol_t = (const float*)d_in[4];
  const float* sol_s = (const float*)d_in[5];
  const float* ada_img_w = (const float*)d_in[6];
  const float* ada_img_b = (const float*)d_in[7];
  const float* ada_img_nw = (const float*)d_in[8];
  const float* ada_txt_w = (const float*)d_in[9];
  const float* ada_txt_b = (const float*)d_in[10];
  const float* ada_txt_nw = (const float*)d_in[11];
  const float* txt_qkv_w = (const float*)d_in[12];
  const float* img_qkv_w = (const float*)d_in[13];
  const float* txt_out_w = (const float*)d_in[14];
  const float* img_out_w = (const float*)d_in[15];
  const float* mod_w = (const float*)d_in[16];
  const float* mod_b = (const float*)d_in[17];
  const float* img_n2_w = (const float*)d_in[18];
  const float* txt_n2_w = (const float*)d_in[19];
  const float* img_fc1_w = (const float*)d_in[20];
  const float* img_fc1_b = (const float*)d_in[21];
  const float* img_fc2_w = (const float*)d_in[22];
  const float* img_fc2_b = (const float*)d_in[23];
  const float* txt_fc1_w = (const float*)d_in[24];
  const float* txt_fc1_b = (const float*)d_in[25];
  const float* txt_fc2_w = (const float*)d_in[26];
  const float* txt_fc2_b = (const float*)d_in[27];
  float* out = (float*)d_out;
  char* ws = (char*)d_ws;

  const size_t MB = 1 << 20;
  float* silu_vec = (float*)(ws + 0);
  float* scales = (float*)(ws + 8192);
  float* modb = (float*)(ws + 16384);
  float* e_img = (float*)(ws + 147456);
  float* e_txt = (float*)(ws + 196608);
  unsigned short* wt0 = (unsigned short*)(ws + 1 * MB);    // 32MB txt weights
  unsigned short* wt1 = (unsigned short*)(ws + 33 * MB);   // 32MB img weights
  unsigned short* Opart = (unsigned short*)(ws + 1 * MB);  // overlays weights (dead then)
  float* mlbuf = (float*)(ws + 42 * MB);                   // 1.25MB
  unsigned short* actA = (unsigned short*)(ws + 65 * MB);  // [2560][2048] bf16, 10MB
  char* attn_base = ws + 75 * MB;                          // 50MB region
  unsigned short* q_txt = (unsigned short*)(attn_base);
  unsigned short* q_img = (unsigned short*)(attn_base + 2 * MB);
  unsigned short* k_cat = (unsigned short*)(attn_base + 10 * MB);
  unsigned short* v_cat = (unsigned short*)(attn_base + 20 * MB);
  unsigned short* vT = (unsigned short*)(attn_base + 30 * MB);
  unsigned short* ao = (unsigned short*)(attn_base + 40 * MB);
  unsigned short* actB = (unsigned short*)attn_base;  // [2560][8192] bf16 (MLP phase)
  float* Cbuf = (float*)(ws + 125 * MB);  // [2560][2048] f32 = 20MB
  const size_t PSTR = (size_t)2560 * 2048;
  (void)PSTR;

  prep_small<<<1, 256, 0, stream>>>(vec, sol_t, silu_vec, scales);
  mod_kernel<<<128, 256, 0, stream>>>(sol_s, mod_w, mod_b, modb);
  ada_gemv<<<dim3(192, 2), 256, 0, stream>>>(silu_vec, ada_img_w, ada_img_b,
                                             ada_txt_w, ada_txt_b, e_img, e_txt);
  norm1_kernel<<<2560, 256, 0, stream>>>(txt, img, ada_txt_nw, ada_img_nw,
                                         e_txt, e_img, actA);
  transpose_w<<<dim3(192, 32), 256, 0, stream>>>(txt_qkv_w, wt0, 2048, 6144);
  transpose_w<<<dim3(192, 32), 256, 0, stream>>>(img_qkv_w, wt1, 2048, 6144);
  {
    GemmP p = {actA, wt0, wt1, nullptr, nullptr, nullptr, nullptr,
               rope, modb, q_txt, q_img, k_cat, v_cat, scales,
               nullptr, nullptr, 4, 6144, 2048, 1};
    gemm2<2><<<dim3(48, 20, 1), 256, 0, stream>>>(p);
  }
  transpose_v<<<dim3(80, 4, 16), dim3(32, 8), 0, stream>>>(v_cat, vT);
  attn_kernel<<<dim3(40, 16, 4), 256, 0, stream>>>(q_txt, q_img, k_cat, vT, Opart, mlbuf);
  attn_merge<<<5120, 256, 0, stream>>>(Opart, mlbuf, ao);
  transpose_w<<<dim3(64, 32), 256, 0, stream>>>(txt_out_w, wt0, 2048, 2048);
  transpose_w<<<dim3(64, 32), 256, 0, stream>>>(img_out_w, wt1, 2048, 2048);
  {
    // out-projection, single-K (320 blocks, all co-resident)
    GemmP p = {ao, wt0, wt1, Cbuf, nullptr, nullptr, nullptr,
               nullptr, nullptr, nullptr, nullptr, nullptr, nullptr, nullptr,
               nullptr, nullptr, 4, 2048, 2048, 1};
    gemm2<0><<<dim3(16, 20, 1), 256, 0, stream>>>(p);
  }
  res1_rms<<<2560, 256, 0, stream>>>(txt, img, Cbuf, e_txt, e_img,
                                     txt_n2_w, img_n2_w, out, actA);
  transpose_w<<<dim3(256, 32), 256, 0, stream>>>(txt_fc1_w, wt0, 2048, 8192);
  transpose_w<<<dim3(256, 32), 256, 0, stream>>>(img_fc1_w, wt1, 2048, 8192);
  {
    GemmP p = {actA, wt0, wt1, nullptr, actB, txt_fc1_b, img_fc1_b,
               nullptr, nullptr, nullptr, nullptr, nullptr, nullptr, nullptr,
               nullptr, nullptr, 4, 8192, 2048, 1};
    gemm2<1><<<dim3(64, 20, 1), 256, 0, stream>>>(p);
  }
  transpose_w<<<dim3(64, 128), 256, 0, stream>>>(txt_fc2_w, wt0, 8192, 2048);
  transpose_w<<<dim3(64, 128), 256, 0, stream>>>(img_fc2_w, wt1, 8192, 2048);
  {
    // fc2, single-K, fused residual2 epilogue (out += g*(C+bias))
    GemmP p = {actB, wt0, wt1, out, nullptr, txt_fc2_b, img_fc2_b,
               nullptr, nullptr, nullptr, nullptr, nullptr, nullptr, nullptr,
               e_txt, e_img, 4, 2048, 8192, 1};
    gemm2<3><<<dim3(16, 20, 1), 256, 0, stream>>>(p);
  }
}

// Round 20
// 691.163 us; speedup vs baseline: 1.0345x; 1.0149x over previous
//
#include <hip/hip_runtime.h>

typedef short short8 __attribute__((ext_vector_type(8)));
typedef float f32x4 __attribute__((ext_vector_type(4)));

__device__ __forceinline__ unsigned short f2bu(float f) {
  unsigned u = __builtin_bit_cast(unsigned, f);
  u += 0x7fffu + ((u >> 16) & 1u);
  return (unsigned short)(u >> 16);
}

// truncating bf16 pack (1 VALU op) — for paths where bias cancels (softmax P / O)
__device__ __forceinline__ unsigned short f2bt(float f) {
  return (unsigned short)(__builtin_bit_cast(unsigned, f) >> 16);
}

__device__ __forceinline__ float b2f(unsigned short b) {
  unsigned u = (unsigned)b << 16;
  return __builtin_bit_cast(float, u);
}

__device__ __forceinline__ float gelu_t(float x) {
  float x3 = x * x * x;
  float t = tanhf(0.7978845608028654f * (x + 0.044715f * x3));
  return 0.5f * x * (1.f + t);
}

__device__ __forceinline__ void gload16(const void* g, void* l) {
  __builtin_amdgcn_global_load_lds(
      (const __attribute__((address_space(1))) void*)g,
      (__attribute__((address_space(3))) void*)l, 16, 0, 0);
}

// ---------------- small prep ----------------
__global__ __launch_bounds__(256) void prep_small(
    const float* __restrict__ vec, const float* __restrict__ sol_t,
    float* __restrict__ silu_vec, float* __restrict__ scales) {
  __shared__ float red[4];
  int t = threadIdx.x;
  float v = (t < 64) ? sol_t[t] : 0.f;
#pragma unroll
  for (int o = 32; o > 0; o >>= 1) v += __shfl_down(v, o);
  if ((t & 63) == 0) red[t >> 6] = v;
  __syncthreads();
  if (t == 0) {
    float m = (red[0] + red[1] + red[2] + red[3]) * (1.f / 64.f);
    m = fmaxf(m, 0.1f);
    const float sc = 0.08838834764831845f;   // 128^-0.5
    const float l2e = 1.4426950408889634f;   // scores computed in log2 domain
    scales[0] = sc * l2e;
    scales[1] = sc / m * l2e;
  }
  for (int k = t; k < 2048; k += 256) {
    float x = vec[k];
    silu_vec[k] = x / (1.f + expf(-x));
  }
}

__global__ __launch_bounds__(256) void mod_kernel(
    const float* __restrict__ S, const float* __restrict__ mw,
    const float* __restrict__ mb, float* __restrict__ modb) {
  int idx = blockIdx.x * 256 + threadIdx.x;  // 16*2048
  int h = idx >> 11, n = idx & 2047;
  int y = n >> 5, x = n & 31;
  float cy = (y + 0.5f) * 0.125f - 0.5f;
  float cx = (x + 0.5f) * 0.25f - 0.5f;
  int y0 = (int)floorf(cy); float fy = cy - (float)y0;
  int x0 = (int)floorf(cx); float fx = cx - (float)x0;
  int y0c = min(max(y0, 0), 7), y1c = min(max(y0 + 1, 0), 7);
  int x0c = min(max(x0, 0), 7), x1c = min(max(x0 + 1, 0), 7);
  float v = (1.f - fy) * ((1.f - fx) * S[y0c * 8 + x0c] + fx * S[y0c * 8 + x1c]) +
            fy * ((1.f - fx) * S[y1c * 8 + x0c] + fx * S[y1c * 8 + x1c]);
  float t = v * mw[h] + mb[h];
  t = fminf(fmaxf(t, -2.f), 2.f);
  modb[idx] = expf(t);
}

__global__ __launch_bounds__(256) void ada_gemv(
    const float* __restrict__ sv,
    const float* __restrict__ Wi, const float* __restrict__ bi,
    const float* __restrict__ Wt, const float* __restrict__ bt,
    float* __restrict__ ei, float* __restrict__ et) {
  __shared__ float red[4][64];
  const float* W = blockIdx.y ? Wt : Wi;
  const float* bb = blockIdx.y ? bt : bi;
  float* e = blockIdx.y ? et : ei;
  int jl = threadIdx.x & 63, ks = threadIdx.x >> 6;
  int j = blockIdx.x * 64 + jl;
  float acc = 0.f;
  int k0 = ks * 512;
#pragma unroll 4
  for (int k = 0; k < 512; ++k) acc += sv[k0 + k] * W[(size_t)(k0 + k) * 12288 + j];
  red[ks][jl] = acc;
  __syncthreads();
  if (ks == 0) e[j] = red[0][jl] + red[1][jl] + red[2][jl] + red[3][jl] + bb[j];
}

// ---------------- norm1: RMSNorm + adaLN modulate (txt+img merged) -> bf16 ----------
__global__ __launch_bounds__(256) void norm1_kernel(
    const float* __restrict__ txt, const float* __restrict__ img,
    const float* __restrict__ nw_t, const float* __restrict__ nw_i,
    const float* __restrict__ e_t, const float* __restrict__ e_i,
    unsigned short* __restrict__ out) {
  __shared__ float red[4];
  int r = blockIdx.x, t = threadIdx.x;
  bool ist = r < 512;
  const float* X = ist ? txt + (size_t)r * 2048 : img + (size_t)(r - 512) * 2048;
  const float* nw = ist ? nw_t : nw_i;
  const float* e = ist ? e_t : e_i;
  const float4* xr = reinterpret_cast<const float4*>(X);
  float4 v0 = xr[t * 2], v1 = xr[t * 2 + 1];
  float ss = v0.x * v0.x + v0.y * v0.y + v0.z * v0.z + v0.w * v0.w +
             v1.x * v1.x + v1.y * v1.y + v1.z * v1.z + v1.w * v1.w;
#pragma unroll
  for (int o = 32; o > 0; o >>= 1) ss += __shfl_down(ss, o);
  if ((t & 63) == 0) red[t >> 6] = ss;
  __syncthreads();
  float rinv = rsqrtf((red[0] + red[1] + red[2] + red[3]) * (1.f / 2048.f) + 1e-6f);
  int c0 = t * 8;
  float xv[8] = {v0.x, v0.y, v0.z, v0.w, v1.x, v1.y, v1.z, v1.w};
  short8 ov;
#pragma unroll
  for (int i = 0; i < 8; ++i) {
    int c = c0 + i;
    float y = xv[i] * rinv * nw[c] * (1.f + e[2048 + c]) + e[c];
    ov[i] = (short)f2bu(y);
  }
  *reinterpret_cast<short8*>(out + (size_t)r * 2048 + c0) = ov;
}

// ---------------- fused residual1 + RMSNorm2+mod (single partial) ----------------
__global__ __launch_bounds__(256) void res1_rms(
    const float* __restrict__ txt, const float* __restrict__ img,
    const float* __restrict__ P0,
    const float* __restrict__ e_t, const float* __restrict__ e_i,
    const float* __restrict__ nw_t, const float* __restrict__ nw_i,
    float* __restrict__ out, unsigned short* __restrict__ actA) {
  __shared__ float red[4];
  int r = blockIdx.x, t = threadIdx.x;
  bool ist = r < 512;
  const float* X = ist ? txt + (size_t)r * 2048 : img + (size_t)(r - 512) * 2048;
  const float* e = ist ? e_t : e_i;
  const float* nw = ist ? nw_t : nw_i;
  int c0 = t * 8;
  const float* p0 = P0 + (size_t)r * 2048 + c0;
  float o[8];
  float ss = 0.f;
#pragma unroll
  for (int i = 0; i < 8; i += 4) {
    float4 x = *reinterpret_cast<const float4*>(X + c0 + i);
    float4 a = *reinterpret_cast<const float4*>(p0 + i);
    float4 g = *reinterpret_cast<const float4*>(e + 4096 + c0 + i);
    o[i + 0] = x.x + g.x * a.x;
    o[i + 1] = x.y + g.y * a.y;
    o[i + 2] = x.z + g.z * a.z;
    o[i + 3] = x.w + g.w * a.w;
    ss += o[i] * o[i] + o[i + 1] * o[i + 1] + o[i + 2] * o[i + 2] + o[i + 3] * o[i + 3];
  }
  *reinterpret_cast<float4*>(out + (size_t)r * 2048 + c0) =
      make_float4(o[0], o[1], o[2], o[3]);
  *reinterpret_cast<float4*>(out + (size_t)r * 2048 + c0 + 4) =
      make_float4(o[4], o[5], o[6], o[7]);
#pragma unroll
  for (int of = 32; of > 0; of >>= 1) ss += __shfl_down(ss, of);
  if ((t & 63) == 0) red[t >> 6] = ss;
  __syncthreads();
  float rinv = rsqrtf((red[0] + red[1] + red[2] + red[3]) * (1.f / 2048.f) + 1e-6f);
  short8 ov;
#pragma unroll
  for (int i = 0; i < 8; ++i) {
    int c = c0 + i;
    float y = o[i] * rinv * nw[c] * (1.f + e[8192 + c]) + e[6144 + c];
    ov[i] = (short)f2bu(y);
  }
  *reinterpret_cast<short8*>(actA + (size_t)r * 2048 + c0) = ov;
}

// ---------------- weight transpose+convert v2: f32 [K][N] -> bf16 [N][K] ------------
// 64x64 tiles, float4 reads, [64][65] LDS (odd stride: conflict-free col read-out),
// 2x int4 writes/thread; z batches the txt/img weight pair.
__global__ __launch_bounds__(256) void transpose_w2(
    const float* __restrict__ W0, const float* __restrict__ W1,
    unsigned short* __restrict__ B0, unsigned short* __restrict__ B1,
    int K, int N) {
  __shared__ float tile[64][65];
  const float* W = blockIdx.z ? W1 : W0;
  unsigned short* Bt = blockIdx.z ? B1 : B0;
  int n0 = blockIdx.x * 64, k0 = blockIdx.y * 64;
  int t = threadIdx.x;
  int rn = (t & 15) * 4, rk = t >> 4;
#pragma unroll
  for (int j = 0; j < 4; ++j) {
    float4 v = *reinterpret_cast<const float4*>(
        W + (size_t)(k0 + rk + j * 16) * N + n0 + rn);
    tile[rk + j * 16][rn + 0] = v.x;
    tile[rk + j * 16][rn + 1] = v.y;
    tile[rk + j * 16][rn + 2] = v.z;
    tile[rk + j * 16][rn + 3] = v.w;
  }
  __syncthreads();
  int wn = t >> 2, wk = (t & 3) * 16;
  unsigned pk[8];
#pragma unroll
  for (int i = 0; i < 8; ++i) {
    float lo = tile[wk + 2 * i][wn], hi = tile[wk + 2 * i + 1][wn];
    pk[i] = (unsigned)f2bu(lo) | ((unsigned)f2bu(hi) << 16);
  }
  unsigned short* dst = Bt + (size_t)(n0 + wn) * K + k0 + wk;
  *reinterpret_cast<int4*>(dst) = make_int4(pk[0], pk[1], pk[2], pk[3]);
  *reinterpret_cast<int4*>(dst + 8) = make_int4(pk[4], pk[5], pk[6], pk[7]);
}

__global__ __launch_bounds__(256) void transpose_v(
    const unsigned short* __restrict__ V, unsigned short* __restrict__ Vt) {
  __shared__ unsigned short tile[32][33];
  int h = blockIdx.z;
  int s0 = blockIdx.x * 32, d0 = blockIdx.y * 32;
  int tx = threadIdx.x, ty = threadIdx.y;
  const unsigned short* src = V + (size_t)h * 2560 * 128;
  unsigned short* dst = Vt + (size_t)h * 128 * 2560;
#pragma unroll
  for (int j = 0; j < 32; j += 8)
    tile[ty + j][tx] = src[(size_t)(s0 + ty + j) * 128 + d0 + tx];
  __syncthreads();
#pragma unroll
  for (int j = 0; j < 32; j += 8)
    dst[(size_t)(d0 + ty + j) * 2560 + s0 + tx] = tile[tx][ty + j];
}

// ---------------- batched GEMM (txt rows 0..511, img rows 512..2559) ----------------
// EPI 0: f32 store. EPI 1: bf16 gelu(acc+bias). EPI 2: qkv scatter. EPI 3: fused res2.
struct GemmP {
  const unsigned short *A, *Bt_t, *Bt_i;
  float* C;            // EPI0: partial base; EPI3: 'out' (RMW)
  unsigned short* Cb;
  const float *bias_t, *bias_i;
  const float *rope, *modb;
  unsigned short *q_txt, *q_img, *k_cat, *v_cat;
  const float* scales;
  const float *ga_t, *ga_i;  // EPI3 gate arrays (e_txt, e_img)
  int Mb_t;
  int N, K, KS;
};

template <int EPI>
__global__ __launch_bounds__(256) void gemm2(GemmP p) {
  __shared__ __align__(16) char GRAW[65536];
  int4* sAb = reinterpret_cast<int4*>(GRAW);            // [2][1024] int4 (32KB)
  int4* sBb = reinterpret_cast<int4*>(GRAW + 32768);    // [2][1024] int4 (32KB)
  const int NB = gridDim.x, MBT = gridDim.y;
  int nwg = NB * MBT;
  int orig = blockIdx.y * NB + blockIdx.x;
  int qq = nwg >> 3, rr = nwg & 7, xcd = orig & 7, base = orig >> 3;
  int sw = (xcd < rr ? xcd * (qq + 1) : rr * (qq + 1) + (xcd - rr) * qq) + base;
  int bx = sw / MBT, by = sw % MBT;
  const bool is_t = by < p.Mb_t;
  const unsigned short* Bt = is_t ? p.Bt_t : p.Bt_i;
  const int m0 = by * 128, n0 = bx * 128;
  const int z = blockIdx.z;
  const int Kz = p.K / p.KS, kbeg = z * Kz, kend = kbeg + Kz;
  const int tid = threadIdx.x;
  const int w = tid >> 6, l = tid & 63, lr = l & 15, lg = l >> 4;
  const int wm = (w >> 1) * 64, wn = (w & 1) * 64;
  f32x4 acc[4][4] = {};
  const int4* Ag = reinterpret_cast<const int4*>(p.A);
  const int4* Bg = reinterpret_cast<const int4*>(Bt);
  const int K8 = p.K >> 3;
  int srow[4], sch[4];
#pragma unroll
  for (int i = 0; i < 4; ++i) {
    int s = i * 256 + tid;
    srow[i] = s >> 3;
    sch[i] = (s & 7) ^ (srow[i] & 7);
  }
  {
    int kc = kbeg >> 3;
#pragma unroll
    for (int i = 0; i < 4; ++i) {
      gload16(&Ag[(size_t)(m0 + srow[i]) * K8 + kc + sch[i]], &sAb[i * 256 + w * 64]);
      gload16(&Bg[(size_t)(n0 + srow[i]) * K8 + kc + sch[i]], &sBb[i * 256 + w * 64]);
    }
  }
  asm volatile("s_waitcnt vmcnt(0)" ::: "memory");
  __builtin_amdgcn_sched_barrier(0);
  __builtin_amdgcn_s_barrier();
  int cur = 0;
  for (int k0 = kbeg; k0 < kend; k0 += 64) {
    if (k0 + 64 < kend) {
      int kc = (k0 + 64) >> 3;
      int nb = (cur ^ 1) * 1024;
#pragma unroll
      for (int i = 0; i < 4; ++i) {
        gload16(&Ag[(size_t)(m0 + srow[i]) * K8 + kc + sch[i]], &sAb[nb + i * 256 + w * 64]);
        gload16(&Bg[(size_t)(n0 + srow[i]) * K8 + kc + sch[i]], &sBb[nb + i * 256 + w * 64]);
      }
      __builtin_amdgcn_sched_barrier(0);
    }
    const short8* pA = reinterpret_cast<const short8*>(sAb + cur * 1024);
    const short8* pB = reinterpret_cast<const short8*>(sBb + cur * 1024);
    __builtin_amdgcn_s_setprio(1);
#pragma unroll
    for (int kk = 0; kk < 2; ++kk) {
      short8 af[4], bf[4];
#pragma unroll
      for (int m = 0; m < 4; ++m) {
        int row = wm + m * 16 + lr;
        af[m] = pA[row * 8 + ((kk * 4 + lg) ^ (row & 7))];
      }
#pragma unroll
      for (int n = 0; n < 4; ++n) {
        int row = wn + n * 16 + lr;
        bf[n] = pB[row * 8 + ((kk * 4 + lg) ^ (row & 7))];
      }
#pragma unroll
      for (int m = 0; m < 4; ++m)
#pragma unroll
        for (int n = 0; n < 4; ++n)
          acc[m][n] = __builtin_amdgcn_mfma_f32_16x16x32_bf16(af[m], bf[n], acc[m][n], 0, 0, 0);
    }
    __builtin_amdgcn_s_setprio(0);
    asm volatile("s_waitcnt vmcnt(0)" ::: "memory");  // next tile landed
    __builtin_amdgcn_sched_barrier(0);
    __builtin_amdgcn_s_barrier();
    cur ^= 1;
  }
  if (EPI == 0) {
    float* C = p.C + (size_t)z * MBT * 128 * p.N;
#pragma unroll
    for (int m = 0; m < 4; ++m)
#pragma unroll
      for (int n = 0; n < 4; ++n)
#pragma unroll
        for (int j = 0; j < 4; ++j) {
          int r = m0 + wm + m * 16 + lg * 4 + j;
          int cc = n0 + wn + n * 16 + lr;
          C[(size_t)r * p.N + cc] = acc[m][n][j];
        }
  } else if (EPI == 1) {
    const float* bias = is_t ? p.bias_t : p.bias_i;
#pragma unroll
    for (int n = 0; n < 4; ++n) {
      int cc = n0 + wn + n * 16 + lr;
      float bv = bias[cc];
#pragma unroll
      for (int m = 0; m < 4; ++m)
#pragma unroll
        for (int j = 0; j < 4; ++j) {
          int r = m0 + wm + m * 16 + lg * 4 + j;
          p.Cb[(size_t)r * p.N + cc] = f2bu(gelu_t(acc[m][n][j] + bv));
        }
    }
  } else if (EPI == 3) {
    // fused residual2: out += g*(acc+bias), staged through LDS bf16, coalesced RMW
    unsigned short* osh = reinterpret_cast<unsigned short*>(GRAW);  // [128][136]
#pragma unroll
    for (int m = 0; m < 4; ++m)
#pragma unroll
      for (int n = 0; n < 4; ++n)
#pragma unroll
        for (int j = 0; j < 4; ++j) {
          int row = wm + m * 16 + lg * 4 + j;
          int col = wn + n * 16 + lr;
          osh[row * 136 + col] = f2bu(acc[m][n][j]);
        }
    __syncthreads();
    const float* gat = (is_t ? p.ga_t : p.ga_i) + 10240;
    const float* bias = is_t ? p.bias_t : p.bias_i;
    int row = tid >> 1, d0 = (tid & 1) * 64;
    int r = m0 + row;
    const unsigned short* src = osh + row * 136 + d0;
    float* op = p.C + (size_t)r * p.N + n0 + d0;
#pragma unroll
    for (int i = 0; i < 16; ++i) {
      float4 o = *reinterpret_cast<const float4*>(op + i * 4);
      float4 g = *reinterpret_cast<const float4*>(gat + n0 + d0 + i * 4);
      float4 bv = *reinterpret_cast<const float4*>(bias + n0 + d0 + i * 4);
      o.x += g.x * (b2f(src[i * 4 + 0]) + bv.x);
      o.y += g.y * (b2f(src[i * 4 + 1]) + bv.y);
      o.z += g.z * (b2f(src[i * 4 + 2]) + bv.z);
      o.w += g.w * (b2f(src[i * 4 + 3]) + bv.w);
      *reinterpret_cast<float4*>(op + i * 4) = o;
    }
  } else {
    unsigned short* osh = reinterpret_cast<unsigned short*>(GRAW);  // [128][136]
#pragma unroll
    for (int m = 0; m < 4; ++m)
#pragma unroll
      for (int n = 0; n < 4; ++n)
#pragma unroll
        for (int j = 0; j < 4; ++j) {
          int row = wm + m * 16 + lg * 4 + j;
          int col = wn + n * 16 + lr;
          osh[row * 136 + col] = f2bu(acc[m][n][j]);
        }
    __syncthreads();
    int sel = bx >> 4, h = bx & 15;
    int row = tid >> 1, d0 = (tid & 1) * 64;
    int r = m0 + row;
    const unsigned short* src = osh + row * 136 + d0;
    if (is_t) {
      if (sel == 0) {
        float qs = p.scales[0];
        unsigned short* dst = p.q_txt + ((size_t)h * 512 + r) * 128 + d0;
#pragma unroll
        for (int i = 0; i < 8; ++i) {
          short8 v = *reinterpret_cast<const short8*>(src + i * 8);
          short8 o;
#pragma unroll
          for (int t = 0; t < 8; ++t)
            o[t] = (short)f2bu(b2f((unsigned short)v[t]) * qs);
          *reinterpret_cast<short8*>(dst + i * 8) = o;
        }
      } else {
        unsigned short* dst =
            (sel == 1 ? p.k_cat : p.v_cat) + ((size_t)h * 2560 + r) * 128 + d0;
#pragma unroll
        for (int i = 0; i < 8; ++i)
          *reinterpret_cast<short8*>(dst + i * 8) =
              *reinterpret_cast<const short8*>(src + i * 8);
      }
    } else {
      int s = r - 512;
      if (sel == 2) {
        unsigned short* dst = p.v_cat + ((size_t)h * 2560 + r) * 128 + d0;
#pragma unroll
        for (int i = 0; i < 8; ++i)
          *reinterpret_cast<short8*>(dst + i * 8) =
              *reinterpret_cast<const short8*>(src + i * 8);
      } else {
        float mv = p.modb[h * 2048 + s];
        float qs = (sel == 0) ? p.scales[1] * mv : mv;
        const float2* rp = reinterpret_cast<const float2*>(p.rope + (size_t)s * 128 + d0);
        unsigned short* dst = (sel == 0)
            ? p.q_img + ((size_t)h * 2048 + s) * 128 + d0
            : p.k_cat + ((size_t)h * 2560 + r) * 128 + d0;
#pragma unroll
        for (int i = 0; i < 8; ++i) {
          short8 v = *reinterpret_cast<const short8*>(src + i * 8);
          short8 o;
#pragma unroll
          for (int t = 0; t < 4; ++t) {
            float2 cs = rp[i * 4 + t];
            float e = b2f((unsigned short)v[2 * t]);
            float od = b2f((unsigned short)v[2 * t + 1]);
            o[2 * t] = (short)f2bu((e * cs.x - od * cs.y) * qs);
            o[2 * t + 1] = (short)f2bu((od * cs.x + e * cs.y) * qs);
          }
          *reinterpret_cast<short8*>(dst + i * 8) = o;
        }
      }
    }
  }
}

// ---------------- split-KV flash attention (QBLK=64, z=4, phase-pipelined) ----------
__global__ __launch_bounds__(256, 4) void attn_kernel(
    const unsigned short* __restrict__ q_txt, const unsigned short* __restrict__ q_img,
    const unsigned short* __restrict__ Kc, const unsigned short* __restrict__ Vt,
    unsigned short* __restrict__ Op, float* __restrict__ ml) {
  __shared__ __align__(16) char RAW[40960];
  int4* sK = reinterpret_cast<int4*>(RAW);            // [64 kv][16 int4] 16KB
  int4* sV = reinterpret_cast<int4*>(RAW + 16384);    // [128 d][8 int4] 16KB
  int4* sP = reinterpret_cast<int4*>(RAW + 32768);    // [64 q][8 int4] 8KB
  unsigned short* osh = reinterpret_cast<unsigned short*>(RAW);  // overlay, stride 136
  const int tid = threadIdx.x, w = tid >> 6, l = tid & 63, lr = l & 15, lg = l >> 4;
  int flat = blockIdx.x + 40 * (blockIdx.y + 16 * blockIdx.z);  // [0,2560)
  int sw = (flat & 7) * 320 + (flat >> 3);
  const int bx = sw % 40;
  int hz = sw / 40;
  const int h = hz & 15, z = hz >> 4;
  const bool is_t = bx < 8;
  const int orow = is_t ? bx * 64 : 512 + (bx - 8) * 64;
  const unsigned short* Qp = is_t ? q_txt + ((size_t)h * 512 + bx * 64) * 128
                                  : q_img + ((size_t)h * 2048 + (bx - 8) * 64) * 128;
  short8 aq[4];
#pragma unroll
  for (int ds = 0; ds < 4; ++ds) {
    int row = w * 16 + lr;
    aq[ds] = *reinterpret_cast<const short8*>(Qp + (size_t)row * 128 + ds * 32 + lg * 8);
  }
  const int4* Kg = reinterpret_cast<const int4*>(Kc + (size_t)h * 2560 * 128);
  const int4* Vg = reinterpret_cast<const int4*>(Vt + (size_t)h * 128 * 2560);
  const short8* pK = reinterpret_cast<const short8*>(sK);
  const short8* pV = reinterpret_cast<const short8*>(sV);
  const short8* pP = reinterpret_cast<const short8*>(sP);
  unsigned short* sPb = reinterpret_cast<unsigned short*>(sP);
  int krow[4], kch[4], vrow[4], vch[4];
#pragma unroll
  for (int i = 0; i < 4; ++i) {
    int s = i * 256 + tid;
    krow[i] = s >> 4; kch[i] = (s & 15) ^ (krow[i] & 7);
    vrow[i] = s >> 3; vch[i] = (s & 7) ^ (vrow[i] & 7);
  }
  short8 ones8;
#pragma unroll
  for (int i = 0; i < 8; ++i) ones8[i] = (short)0x3F80;

  f32x4 oacc[8] = {};
  f32x4 oacc_l = {};
  float m_run[4];
#pragma unroll
  for (int j = 0; j < 4; ++j) m_run[j] = -1e30f;

  const int kbeg = z * 10, kend = kbeg + 10;
#pragma unroll
  for (int i = 0; i < 4; ++i)
    gload16(&Kg[(size_t)(kbeg * 64 + krow[i]) * 16 + kch[i]], &sK[i * 256 + w * 64]);
#pragma unroll
  for (int i = 0; i < 4; ++i)
    gload16(&Vg[(size_t)vrow[i] * 320 + kbeg * 8 + vch[i]], &sV[i * 256 + w * 64]);

  for (int kt = kbeg; kt < kend; ++kt) {
    asm volatile("s_waitcnt vmcnt(4)" ::: "memory");
    __builtin_amdgcn_sched_barrier(0);
    __builtin_amdgcn_s_barrier();
    f32x4 sacc[4] = {};
    __builtin_amdgcn_s_setprio(1);
#pragma unroll
    for (int ds = 0; ds < 4; ++ds) {
      short8 bk[4];
#pragma unroll
      for (int n = 0; n < 4; ++n) {
        int row = n * 16 + lr;
        bk[n] = pK[row * 16 + ((ds * 4 + lg) ^ (row & 7))];
      }
#pragma unroll
      for (int n = 0; n < 4; ++n)
        sacc[n] = __builtin_amdgcn_mfma_f32_16x16x32_bf16(aq[ds], bk[n], sacc[n], 0, 0, 0);
    }
    __builtin_amdgcn_s_setprio(0);
    __builtin_amdgcn_s_barrier();  // release sK
    if (kt + 1 < kend) {
#pragma unroll
      for (int i = 0; i < 4; ++i)
        gload16(&Kg[(size_t)((kt + 1) * 64 + krow[i]) * 16 + kch[i]], &sK[i * 256 + w * 64]);
    }
    float corr_[4];
    bool grow_any = false;
#pragma unroll
    for (int j = 0; j < 4; ++j) {
      float mx = fmaxf(fmaxf(sacc[0][j], sacc[1][j]), fmaxf(sacc[2][j], sacc[3][j]));
      mx = fmaxf(mx, __shfl_xor(mx, 1));
      mx = fmaxf(mx, __shfl_xor(mx, 2));
      mx = fmaxf(mx, __shfl_xor(mx, 4));
      mx = fmaxf(mx, __shfl_xor(mx, 8));
      bool grow = mx > m_run[j] + 11.0f;
      grow_any |= grow;
      float mn = grow ? mx : m_run[j];
      corr_[j] = grow ? exp2f(m_run[j] - mn) : 1.0f;
      m_run[j] = mn;
      int prow = w * 16 + lg * 4 + j;
#pragma unroll
      for (int n = 0; n < 4; ++n) {
        float pp = exp2f(sacc[n][j] - mn);
        int col = n * 16 + lr;
        sPb[prow * 64 + (((col >> 3) ^ (prow & 7)) << 3) + (col & 7)] = f2bt(pp);
      }
    }
    if (__any(grow_any)) {
#pragma unroll
      for (int n = 0; n < 8; ++n)
#pragma unroll
        for (int j = 0; j < 4; ++j) oacc[n][j] *= corr_[j];
#pragma unroll
      for (int j = 0; j < 4; ++j) oacc_l[j] *= corr_[j];
    }
    if (kt + 1 < kend) {
      asm volatile("s_waitcnt vmcnt(4)" ::: "memory");
    } else {
      asm volatile("s_waitcnt vmcnt(0)" ::: "memory");
    }
    __builtin_amdgcn_sched_barrier(0);
    __builtin_amdgcn_s_barrier();
    __builtin_amdgcn_s_setprio(1);
#pragma unroll
    for (int kk = 0; kk < 2; ++kk) {
      short8 ap, bv[8];
      {
        int row = w * 16 + lr;
        ap = pP[row * 8 + ((kk * 4 + lg) ^ (row & 7))];
      }
#pragma unroll
      for (int n = 0; n < 8; ++n) {
        int row = n * 16 + lr;
        bv[n] = pV[row * 8 + ((kk * 4 + lg) ^ (row & 7))];
      }
#pragma unroll
      for (int n = 0; n < 8; ++n)
        oacc[n] = __builtin_amdgcn_mfma_f32_16x16x32_bf16(ap, bv[n], oacc[n], 0, 0, 0);
      oacc_l = __builtin_amdgcn_mfma_f32_16x16x32_bf16(ap, ones8, oacc_l, 0, 0, 0);
    }
    __builtin_amdgcn_s_setprio(0);
    __builtin_amdgcn_s_barrier();  // release sV
    if (kt + 1 < kend) {
#pragma unroll
      for (int i = 0; i < 4; ++i)
        gload16(&Vg[(size_t)vrow[i] * 320 + (kt + 1) * 8 + vch[i]], &sV[i * 256 + w * 64]);
    }
  }
  const size_t zbase = (size_t)z * 40960 + (size_t)h * 2560 + orow;
  __syncthreads();  // sK/sV/sP dead -> osh overlay
#pragma unroll
  for (int j = 0; j < 4; ++j) {
    int row = w * 16 + lg * 4 + j;
#pragma unroll
    for (int n = 0; n < 8; ++n)
      osh[row * 136 + n * 16 + lr] = f2bt(oacc[n][j]);
    if (lr == 0) {
      ml[(zbase + row) * 2] = m_run[j];
      ml[(zbase + row) * 2 + 1] = oacc_l[j];
    }
  }
  __syncthreads();
  {
    int row = tid >> 2, c0 = (tid & 3) * 32;
#pragma unroll
    for (int i = 0; i < 4; ++i)
      *reinterpret_cast<short8*>(Op + (zbase + row) * 128 + c0 + i * 8) =
          *reinterpret_cast<const short8*>(osh + row * 136 + c0 + i * 8);
  }
}

// merge 4 KV-chunk partials (log2-domain LSE combine) -> ao[r][h*128+d] bf16
// 8 cols/thread, short8 I/O.
__global__ __launch_bounds__(256) void attn_merge(
    const unsigned short* __restrict__ Op, const float* __restrict__ ml,
    unsigned short* __restrict__ ao) {
  int gid = blockIdx.x * 256 + threadIdx.x;  // 40960 rows * 16 threads
  int rid = gid >> 4, d0 = (gid & 15) * 8;
  int h = rid / 2560;
  int r = rid - h * 2560;
  float M = -1e30f;
#pragma unroll
  for (int z = 0; z < 4; ++z) M = fmaxf(M, ml[((size_t)z * 40960 + rid) * 2]);
  float L = 0.f;
  float o[8] = {};
#pragma unroll
  for (int z = 0; z < 4; ++z) {
    size_t sidx = (size_t)z * 40960 + rid;
    float mz = ml[sidx * 2], lz = ml[sidx * 2 + 1];
    float wgt = exp2f(mz - M);
    L += wgt * lz;
    short8 v = *reinterpret_cast<const short8*>(Op + sidx * 128 + d0);
#pragma unroll
    for (int i = 0; i < 8; ++i) o[i] += wgt * b2f((unsigned short)v[i]);
  }
  float inv = 1.f / L;
  short8 ov;
#pragma unroll
  for (int i = 0; i < 8; ++i) ov[i] = (short)f2bu(o[i] * inv);
  *reinterpret_cast<short8*>(ao + (size_t)r * 2048 + h * 128 + d0) = ov;
}

extern "C" void kernel_launch(void* const* d_in, const int* in_sizes, int n_in,
                              void* d_out, int out_size, void* d_ws, size_t ws_size,
                              hipStream_t stream) {
  (void)in_sizes; (void)n_in; (void)out_size; (void)ws_size;
  const float* txt = (const float*)d_in[0];
  const float* img = (const float*)d_in[1];
  const float* vec = (const float*)d_in[2];
  const float* rope = (const float*)d_in[3];
  const float* sol_t = (const float*)d_in[4];
  const float* sol_s = (const float*)d_in[5];
  const float* ada_img_w = (const float*)d_in[6];
  const float* ada_img_b = (const float*)d_in[7];
  const float* ada_img_nw = (const float*)d_in[8];
  const float* ada_txt_w = (const float*)d_in[9];
  const float* ada_txt_b = (const float*)d_in[10];
  const float* ada_txt_nw = (const float*)d_in[11];
  const float* txt_qkv_w = (const float*)d_in[12];
  const float* img_qkv_w = (const float*)d_in[13];
  const float* txt_out_w = (const float*)d_in[14];
  const float* img_out_w = (const float*)d_in[15];
  const float* mod_w = (const float*)d_in[16];
  const float* mod_b = (const float*)d_in[17];
  const float* img_n2_w = (const float*)d_in[18];
  const float* txt_n2_w = (const float*)d_in[19];
  const float* img_fc1_w = (const float*)d_in[20];
  const float* img_fc1_b = (const float*)d_in[21];
  const float* img_fc2_w = (const float*)d_in[22];
  const float* img_fc2_b = (const float*)d_in[23];
  const float* txt_fc1_w = (const float*)d_in[24];
  const float* txt_fc1_b = (const float*)d_in[25];
  const float* txt_fc2_w = (const float*)d_in[26];
  const float* txt_fc2_b = (const float*)d_in[27];
  float* out = (float*)d_out;
  char* ws = (char*)d_ws;

  const size_t MB = 1 << 20;
  float* silu_vec = (float*)(ws + 0);
  float* scales = (float*)(ws + 8192);
  float* modb = (float*)(ws + 16384);
  float* e_img = (float*)(ws + 147456);
  float* e_txt = (float*)(ws + 196608);
  unsigned short* wt0 = (unsigned short*)(ws + 1 * MB);    // 32MB txt weights
  unsigned short* wt1 = (unsigned short*)(ws + 33 * MB);   // 32MB img weights
  unsigned short* Opart = (unsigned short*)(ws + 1 * MB);  // overlays weights (dead then)
  float* mlbuf = (float*)(ws + 42 * MB);                   // 1.25MB
  unsigned short* actA = (unsigned short*)(ws + 65 * MB);  // [2560][2048] bf16, 10MB
  char* attn_base = ws + 75 * MB;                          // 50MB region
  unsigned short* q_txt = (unsigned short*)(attn_base);
  unsigned short* q_img = (unsigned short*)(attn_base + 2 * MB);
  unsigned short* k_cat = (unsigned short*)(attn_base + 10 * MB);
  unsigned short* v_cat = (unsigned short*)(attn_base + 20 * MB);
  unsigned short* vT = (unsigned short*)(attn_base + 30 * MB);
  unsigned short* ao = (unsigned short*)(attn_base + 40 * MB);
  unsigned short* actB = (unsigned short*)attn_base;  // [2560][8192] bf16 (MLP phase)
  float* Cbuf = (float*)(ws + 125 * MB);  // [2560][2048] f32 = 20MB

  prep_small<<<1, 256, 0, stream>>>(vec, sol_t, silu_vec, scales);
  mod_kernel<<<128, 256, 0, stream>>>(sol_s, mod_w, mod_b, modb);
  ada_gemv<<<dim3(192, 2), 256, 0, stream>>>(silu_vec, ada_img_w, ada_img_b,
                                             ada_txt_w, ada_txt_b, e_img, e_txt);
  norm1_kernel<<<2560, 256, 0, stream>>>(txt, img, ada_txt_nw, ada_img_nw,
                                         e_txt, e_img, actA);
  transpose_w2<<<dim3(96, 32, 2), 256, 0, stream>>>(txt_qkv_w, img_qkv_w,
                                                    wt0, wt1, 2048, 6144);
  {
    GemmP p = {actA, wt0, wt1, nullptr, nullptr, nullptr, nullptr,
               rope, modb, q_txt, q_img, k_cat, v_cat, scales,
               nullptr, nullptr, 4, 6144, 2048, 1};
    gemm2<2><<<dim3(48, 20, 1), 256, 0, stream>>>(p);
  }
  transpose_v<<<dim3(80, 4, 16), dim3(32, 8), 0, stream>>>(v_cat, vT);
  attn_kernel<<<dim3(40, 16, 4), 256, 0, stream>>>(q_txt, q_img, k_cat, vT, Opart, mlbuf);
  attn_merge<<<2560, 256, 0, stream>>>(Opart, mlbuf, ao);
  transpose_w2<<<dim3(32, 32, 2), 256, 0, stream>>>(txt_out_w, img_out_w,
                                                    wt0, wt1, 2048, 2048);
  {
    // out-projection, single-K (320 blocks, all co-resident)
    GemmP p = {ao, wt0, wt1, Cbuf, nullptr, nullptr, nullptr,
               nullptr, nullptr, nullptr, nullptr, nullptr, nullptr, nullptr,
               nullptr, nullptr, 4, 2048, 2048, 1};
    gemm2<0><<<dim3(16, 20, 1), 256, 0, stream>>>(p);
  }
  res1_rms<<<2560, 256, 0, stream>>>(txt, img, Cbuf, e_txt, e_img,
                                     txt_n2_w, img_n2_w, out, actA);
  transpose_w2<<<dim3(128, 32, 2), 256, 0, stream>>>(txt_fc1_w, img_fc1_w,
                                                     wt0, wt1, 2048, 8192);
  {
    GemmP p = {actA, wt0, wt1, nullptr, actB, txt_fc1_b, img_fc1_b,
               nullptr, nullptr, nullptr, nullptr, nullptr, nullptr, nullptr,
               nullptr, nullptr, 4, 8192, 2048, 1};
    gemm2<1><<<dim3(64, 20, 1), 256, 0, stream>>>(p);
  }
  transpose_w2<<<dim3(32, 128, 2), 256, 0, stream>>>(txt_fc2_w, img_fc2_w,
                                                     wt0, wt1, 8192, 2048);
  {
    // fc2, single-K, fused residual2 epilogue (out += g*(C+bias))
    GemmP p = {actB, wt0, wt1, out, nullptr, txt_fc2_b, img_fc2_b,
               nullptr, nullptr, nullptr, nullptr, nullptr, nullptr, nullptr,
               e_txt, e_img, 4, 2048, 8192, 1};
    gemm2<3><<<dim3(16, 20, 1), 256, 0, stream>>>(p);
  }
}

// Round 21
// 690.621 us; speedup vs baseline: 1.0353x; 1.0008x over previous
//
#include <hip/hip_runtime.h>

typedef short short8 __attribute__((ext_vector_type(8)));
typedef float f32x4 __attribute__((ext_vector_type(4)));

__device__ __forceinline__ unsigned short f2bu(float f) {
  unsigned u = __builtin_bit_cast(unsigned, f);
  u += 0x7fffu + ((u >> 16) & 1u);
  return (unsigned short)(u >> 16);
}

// truncating bf16 pack (1 VALU op) — for paths where bias cancels (softmax P / O)
__device__ __forceinline__ unsigned short f2bt(float f) {
  return (unsigned short)(__builtin_bit_cast(unsigned, f) >> 16);
}

__device__ __forceinline__ float b2f(unsigned short b) {
  unsigned u = (unsigned)b << 16;
  return __builtin_bit_cast(float, u);
}

__device__ __forceinline__ float gelu_t(float x) {
  float x3 = x * x * x;
  float t = tanhf(0.7978845608028654f * (x + 0.044715f * x3));
  return 0.5f * x * (1.f + t);
}

__device__ __forceinline__ void gload16(const void* g, void* l) {
  __builtin_amdgcn_global_load_lds(
      (const __attribute__((address_space(1))) void*)g,
      (__attribute__((address_space(3))) void*)l, 16, 0, 0);
}

// ---------------- small prep ----------------
__global__ __launch_bounds__(256) void prep_small(
    const float* __restrict__ vec, const float* __restrict__ sol_t,
    float* __restrict__ silu_vec, float* __restrict__ scales) {
  __shared__ float red[4];
  int t = threadIdx.x;
  float v = (t < 64) ? sol_t[t] : 0.f;
#pragma unroll
  for (int o = 32; o > 0; o >>= 1) v += __shfl_down(v, o);
  if ((t & 63) == 0) red[t >> 6] = v;
  __syncthreads();
  if (t == 0) {
    float m = (red[0] + red[1] + red[2] + red[3]) * (1.f / 64.f);
    m = fmaxf(m, 0.1f);
    const float sc = 0.08838834764831845f;   // 128^-0.5
    const float l2e = 1.4426950408889634f;   // scores computed in log2 domain
    scales[0] = sc * l2e;
    scales[1] = sc / m * l2e;
  }
  for (int k = t; k < 2048; k += 256) {
    float x = vec[k];
    silu_vec[k] = x / (1.f + expf(-x));
  }
}

__global__ __launch_bounds__(256) void mod_kernel(
    const float* __restrict__ S, const float* __restrict__ mw,
    const float* __restrict__ mb, float* __restrict__ modb) {
  int idx = blockIdx.x * 256 + threadIdx.x;  // 16*2048
  int h = idx >> 11, n = idx & 2047;
  int y = n >> 5, x = n & 31;
  float cy = (y + 0.5f) * 0.125f - 0.5f;
  float cx = (x + 0.5f) * 0.25f - 0.5f;
  int y0 = (int)floorf(cy); float fy = cy - (float)y0;
  int x0 = (int)floorf(cx); float fx = cx - (float)x0;
  int y0c = min(max(y0, 0), 7), y1c = min(max(y0 + 1, 0), 7);
  int x0c = min(max(x0, 0), 7), x1c = min(max(x0 + 1, 0), 7);
  float v = (1.f - fy) * ((1.f - fx) * S[y0c * 8 + x0c] + fx * S[y0c * 8 + x1c]) +
            fy * ((1.f - fx) * S[y1c * 8 + x0c] + fx * S[y1c * 8 + x1c]);
  float t = v * mw[h] + mb[h];
  t = fminf(fmaxf(t, -2.f), 2.f);
  modb[idx] = expf(t);
}

__global__ __launch_bounds__(256) void ada_gemv(
    const float* __restrict__ sv,
    const float* __restrict__ Wi, const float* __restrict__ bi,
    const float* __restrict__ Wt, const float* __restrict__ bt,
    float* __restrict__ ei, float* __restrict__ et) {
  __shared__ float red[4][64];
  const float* W = blockIdx.y ? Wt : Wi;
  const float* bb = blockIdx.y ? bt : bi;
  float* e = blockIdx.y ? et : ei;
  int jl = threadIdx.x & 63, ks = threadIdx.x >> 6;
  int j = blockIdx.x * 64 + jl;
  float acc = 0.f;
  int k0 = ks * 512;
#pragma unroll 4
  for (int k = 0; k < 512; ++k) acc += sv[k0 + k] * W[(size_t)(k0 + k) * 12288 + j];
  red[ks][jl] = acc;
  __syncthreads();
  if (ks == 0) e[j] = red[0][jl] + red[1][jl] + red[2][jl] + red[3][jl] + bb[j];
}

// ---------------- norm1: RMSNorm + adaLN modulate (txt+img merged) -> bf16 ----------
__global__ __launch_bounds__(256) void norm1_kernel(
    const float* __restrict__ txt, const float* __restrict__ img,
    const float* __restrict__ nw_t, const float* __restrict__ nw_i,
    const float* __restrict__ e_t, const float* __restrict__ e_i,
    unsigned short* __restrict__ out) {
  __shared__ float red[4];
  int r = blockIdx.x, t = threadIdx.x;
  bool ist = r < 512;
  const float* X = ist ? txt + (size_t)r * 2048 : img + (size_t)(r - 512) * 2048;
  const float* nw = ist ? nw_t : nw_i;
  const float* e = ist ? e_t : e_i;
  const float4* xr = reinterpret_cast<const float4*>(X);
  float4 v0 = xr[t * 2], v1 = xr[t * 2 + 1];
  float ss = v0.x * v0.x + v0.y * v0.y + v0.z * v0.z + v0.w * v0.w +
             v1.x * v1.x + v1.y * v1.y + v1.z * v1.z + v1.w * v1.w;
#pragma unroll
  for (int o = 32; o > 0; o >>= 1) ss += __shfl_down(ss, o);
  if ((t & 63) == 0) red[t >> 6] = ss;
  __syncthreads();
  float rinv = rsqrtf((red[0] + red[1] + red[2] + red[3]) * (1.f / 2048.f) + 1e-6f);
  int c0 = t * 8;
  float xv[8] = {v0.x, v0.y, v0.z, v0.w, v1.x, v1.y, v1.z, v1.w};
  short8 ov;
#pragma unroll
  for (int i = 0; i < 8; ++i) {
    int c = c0 + i;
    float y = xv[i] * rinv * nw[c] * (1.f + e[2048 + c]) + e[c];
    ov[i] = (short)f2bu(y);
  }
  *reinterpret_cast<short8*>(out + (size_t)r * 2048 + c0) = ov;
}

// ---------------- fused residual1 + RMSNorm2+mod (single partial) ----------------
__global__ __launch_bounds__(256) void res1_rms(
    const float* __restrict__ txt, const float* __restrict__ img,
    const float* __restrict__ P0,
    const float* __restrict__ e_t, const float* __restrict__ e_i,
    const float* __restrict__ nw_t, const float* __restrict__ nw_i,
    float* __restrict__ out, unsigned short* __restrict__ actA) {
  __shared__ float red[4];
  int r = blockIdx.x, t = threadIdx.x;
  bool ist = r < 512;
  const float* X = ist ? txt + (size_t)r * 2048 : img + (size_t)(r - 512) * 2048;
  const float* e = ist ? e_t : e_i;
  const float* nw = ist ? nw_t : nw_i;
  int c0 = t * 8;
  const float* p0 = P0 + (size_t)r * 2048 + c0;
  float o[8];
  float ss = 0.f;
#pragma unroll
  for (int i = 0; i < 8; i += 4) {
    float4 x = *reinterpret_cast<const float4*>(X + c0 + i);
    float4 a = *reinterpret_cast<const float4*>(p0 + i);
    float4 g = *reinterpret_cast<const float4*>(e + 4096 + c0 + i);
    o[i + 0] = x.x + g.x * a.x;
    o[i + 1] = x.y + g.y * a.y;
    o[i + 2] = x.z + g.z * a.z;
    o[i + 3] = x.w + g.w * a.w;
    ss += o[i] * o[i] + o[i + 1] * o[i + 1] + o[i + 2] * o[i + 2] + o[i + 3] * o[i + 3];
  }
  *reinterpret_cast<float4*>(out + (size_t)r * 2048 + c0) =
      make_float4(o[0], o[1], o[2], o[3]);
  *reinterpret_cast<float4*>(out + (size_t)r * 2048 + c0 + 4) =
      make_float4(o[4], o[5], o[6], o[7]);
#pragma unroll
  for (int of = 32; of > 0; of >>= 1) ss += __shfl_down(ss, of);
  if ((t & 63) == 0) red[t >> 6] = ss;
  __syncthreads();
  float rinv = rsqrtf((red[0] + red[1] + red[2] + red[3]) * (1.f / 2048.f) + 1e-6f);
  short8 ov;
#pragma unroll
  for (int i = 0; i < 8; ++i) {
    int c = c0 + i;
    float y = o[i] * rinv * nw[c] * (1.f + e[8192 + c]) + e[6144 + c];
    ov[i] = (short)f2bu(y);
  }
  *reinterpret_cast<short8*>(actA + (size_t)r * 2048 + c0) = ov;
}

// ---------------- weight transpose+convert v2: f32 [K][N] -> bf16 [N][K] ------------
__global__ __launch_bounds__(256) void transpose_w2(
    const float* __restrict__ W0, const float* __restrict__ W1,
    unsigned short* __restrict__ B0, unsigned short* __restrict__ B1,
    int K, int N) {
  __shared__ float tile[64][65];
  const float* W = blockIdx.z ? W1 : W0;
  unsigned short* Bt = blockIdx.z ? B1 : B0;
  int n0 = blockIdx.x * 64, k0 = blockIdx.y * 64;
  int t = threadIdx.x;
  int rn = (t & 15) * 4, rk = t >> 4;
#pragma unroll
  for (int j = 0; j < 4; ++j) {
    float4 v = *reinterpret_cast<const float4*>(
        W + (size_t)(k0 + rk + j * 16) * N + n0 + rn);
    tile[rk + j * 16][rn + 0] = v.x;
    tile[rk + j * 16][rn + 1] = v.y;
    tile[rk + j * 16][rn + 2] = v.z;
    tile[rk + j * 16][rn + 3] = v.w;
  }
  __syncthreads();
  int wn = t >> 2, wk = (t & 3) * 16;
  unsigned pk[8];
#pragma unroll
  for (int i = 0; i < 8; ++i) {
    float lo = tile[wk + 2 * i][wn], hi = tile[wk + 2 * i + 1][wn];
    pk[i] = (unsigned)f2bu(lo) | ((unsigned)f2bu(hi) << 16);
  }
  unsigned short* dst = Bt + (size_t)(n0 + wn) * K + k0 + wk;
  *reinterpret_cast<int4*>(dst) = make_int4(pk[0], pk[1], pk[2], pk[3]);
  *reinterpret_cast<int4*>(dst + 8) = make_int4(pk[4], pk[5], pk[6], pk[7]);
}

__global__ __launch_bounds__(256) void transpose_v(
    const unsigned short* __restrict__ V, unsigned short* __restrict__ Vt) {
  __shared__ unsigned short tile[32][33];
  int h = blockIdx.z;
  int s0 = blockIdx.x * 32, d0 = blockIdx.y * 32;
  int tx = threadIdx.x, ty = threadIdx.y;
  const unsigned short* src = V + (size_t)h * 2560 * 128;
  unsigned short* dst = Vt + (size_t)h * 128 * 2560;
#pragma unroll
  for (int j = 0; j < 32; j += 8)
    tile[ty + j][tx] = src[(size_t)(s0 + ty + j) * 128 + d0 + tx];
  __syncthreads();
#pragma unroll
  for (int j = 0; j < 32; j += 8)
    dst[(size_t)(d0 + ty + j) * 2560 + s0 + tx] = tile[tx][ty + j];
}

// ---------------- batched GEMM (txt rows 0..511, img rows 512..2559) ----------------
// EPI 0: f32 store. EPI 1: bf16 gelu(acc+bias). EPI 2: qkv scatter. EPI 3: fused res2.
struct GemmP {
  const unsigned short *A, *Bt_t, *Bt_i;
  float* C;            // EPI0: partial base; EPI3: 'out' (RMW)
  unsigned short* Cb;
  const float *bias_t, *bias_i;
  const float *rope, *modb;
  unsigned short *q_txt, *q_img, *k_cat, *v_cat;
  const float* scales;
  const float *ga_t, *ga_i;  // EPI3 gate arrays (e_txt, e_img)
  int Mb_t;
  int N, K, KS;
};

template <int EPI>
__global__ __launch_bounds__(256) void gemm2(GemmP p) {
  __shared__ __align__(16) char GRAW[65536];
  int4* sAb = reinterpret_cast<int4*>(GRAW);            // [2][1024] int4 (32KB)
  int4* sBb = reinterpret_cast<int4*>(GRAW + 32768);    // [2][1024] int4 (32KB)
  const int NB = gridDim.x, MBT = gridDim.y;
  int nwg = NB * MBT;
  int orig = blockIdx.y * NB + blockIdx.x;
  int qq = nwg >> 3, rr = nwg & 7, xcd = orig & 7, base = orig >> 3;
  int sw = (xcd < rr ? xcd * (qq + 1) : rr * (qq + 1) + (xcd - rr) * qq) + base;
  int bx = sw / MBT, by = sw % MBT;
  const bool is_t = by < p.Mb_t;
  const unsigned short* Bt = is_t ? p.Bt_t : p.Bt_i;
  const int m0 = by * 128, n0 = bx * 128;
  const int z = blockIdx.z;
  const int Kz = p.K / p.KS, kbeg = z * Kz, kend = kbeg + Kz;
  const int tid = threadIdx.x;
  const int w = tid >> 6, l = tid & 63, lr = l & 15, lg = l >> 4;
  const int wm = (w >> 1) * 64, wn = (w & 1) * 64;
  f32x4 acc[4][4] = {};
  const int4* Ag = reinterpret_cast<const int4*>(p.A);
  const int4* Bg = reinterpret_cast<const int4*>(Bt);
  const int K8 = p.K >> 3;
  int srow[4], sch[4];
#pragma unroll
  for (int i = 0; i < 4; ++i) {
    int s = i * 256 + tid;
    srow[i] = s >> 3;
    sch[i] = (s & 7) ^ (srow[i] & 7);
  }
  {
    int kc = kbeg >> 3;
#pragma unroll
    for (int i = 0; i < 4; ++i) {
      gload16(&Ag[(size_t)(m0 + srow[i]) * K8 + kc + sch[i]], &sAb[i * 256 + w * 64]);
      gload16(&Bg[(size_t)(n0 + srow[i]) * K8 + kc + sch[i]], &sBb[i * 256 + w * 64]);
    }
  }
  asm volatile("s_waitcnt vmcnt(0)" ::: "memory");
  __builtin_amdgcn_sched_barrier(0);
  __builtin_amdgcn_s_barrier();
  int cur = 0;
  for (int k0 = kbeg; k0 < kend; k0 += 64) {
    if (k0 + 64 < kend) {
      int kc = (k0 + 64) >> 3;
      int nb = (cur ^ 1) * 1024;
#pragma unroll
      for (int i = 0; i < 4; ++i) {
        gload16(&Ag[(size_t)(m0 + srow[i]) * K8 + kc + sch[i]], &sAb[nb + i * 256 + w * 64]);
        gload16(&Bg[(size_t)(n0 + srow[i]) * K8 + kc + sch[i]], &sBb[nb + i * 256 + w * 64]);
      }
      __builtin_amdgcn_sched_barrier(0);
    }
    const short8* pA = reinterpret_cast<const short8*>(sAb + cur * 1024);
    const short8* pB = reinterpret_cast<const short8*>(sBb + cur * 1024);
    __builtin_amdgcn_s_setprio(1);
#pragma unroll
    for (int kk = 0; kk < 2; ++kk) {
      short8 af[4], bf[4];
#pragma unroll
      for (int m = 0; m < 4; ++m) {
        int row = wm + m * 16 + lr;
        af[m] = pA[row * 8 + ((kk * 4 + lg) ^ (row & 7))];
      }
#pragma unroll
      for (int n = 0; n < 4; ++n) {
        int row = wn + n * 16 + lr;
        bf[n] = pB[row * 8 + ((kk * 4 + lg) ^ (row & 7))];
      }
#pragma unroll
      for (int m = 0; m < 4; ++m)
#pragma unroll
        for (int n = 0; n < 4; ++n)
          acc[m][n] = __builtin_amdgcn_mfma_f32_16x16x32_bf16(af[m], bf[n], acc[m][n], 0, 0, 0);
    }
    __builtin_amdgcn_s_setprio(0);
    asm volatile("s_waitcnt vmcnt(0)" ::: "memory");  // next tile landed
    __builtin_amdgcn_sched_barrier(0);
    __builtin_amdgcn_s_barrier();
    cur ^= 1;
  }
  if (EPI == 0) {
    float* C = p.C + (size_t)z * MBT * 128 * p.N;
#pragma unroll
    for (int m = 0; m < 4; ++m)
#pragma unroll
      for (int n = 0; n < 4; ++n)
#pragma unroll
        for (int j = 0; j < 4; ++j) {
          int r = m0 + wm + m * 16 + lg * 4 + j;
          int cc = n0 + wn + n * 16 + lr;
          C[(size_t)r * p.N + cc] = acc[m][n][j];
        }
  } else if (EPI == 1) {
    const float* bias = is_t ? p.bias_t : p.bias_i;
#pragma unroll
    for (int n = 0; n < 4; ++n) {
      int cc = n0 + wn + n * 16 + lr;
      float bv = bias[cc];
#pragma unroll
      for (int m = 0; m < 4; ++m)
#pragma unroll
        for (int j = 0; j < 4; ++j) {
          int r = m0 + wm + m * 16 + lg * 4 + j;
          p.Cb[(size_t)r * p.N + cc] = f2bu(gelu_t(acc[m][n][j] + bv));
        }
    }
  } else if (EPI == 3) {
    // fused residual2: out += g*(acc+bias), staged through LDS bf16, coalesced RMW
    unsigned short* osh = reinterpret_cast<unsigned short*>(GRAW);  // [128][136]
#pragma unroll
    for (int m = 0; m < 4; ++m)
#pragma unroll
      for (int n = 0; n < 4; ++n)
#pragma unroll
        for (int j = 0; j < 4; ++j) {
          int row = wm + m * 16 + lg * 4 + j;
          int col = wn + n * 16 + lr;
          osh[row * 136 + col] = f2bu(acc[m][n][j]);
        }
    __syncthreads();
    const float* gat = (is_t ? p.ga_t : p.ga_i) + 10240;
    const float* bias = is_t ? p.bias_t : p.bias_i;
    int row = tid >> 1, d0 = (tid & 1) * 64;
    int r = m0 + row;
    const unsigned short* src = osh + row * 136 + d0;
    float* op = p.C + (size_t)r * p.N + n0 + d0;
#pragma unroll
    for (int i = 0; i < 16; ++i) {
      float4 o = *reinterpret_cast<const float4*>(op + i * 4);
      float4 g = *reinterpret_cast<const float4*>(gat + n0 + d0 + i * 4);
      float4 bv = *reinterpret_cast<const float4*>(bias + n0 + d0 + i * 4);
      o.x += g.x * (b2f(src[i * 4 + 0]) + bv.x);
      o.y += g.y * (b2f(src[i * 4 + 1]) + bv.y);
      o.z += g.z * (b2f(src[i * 4 + 2]) + bv.z);
      o.w += g.w * (b2f(src[i * 4 + 3]) + bv.w);
      *reinterpret_cast<float4*>(op + i * 4) = o;
    }
  } else {
    unsigned short* osh = reinterpret_cast<unsigned short*>(GRAW);  // [128][136]
#pragma unroll
    for (int m = 0; m < 4; ++m)
#pragma unroll
      for (int n = 0; n < 4; ++n)
#pragma unroll
        for (int j = 0; j < 4; ++j) {
          int row = wm + m * 16 + lg * 4 + j;
          int col = wn + n * 16 + lr;
          osh[row * 136 + col] = f2bu(acc[m][n][j]);
        }
    __syncthreads();
    int sel = bx >> 4, h = bx & 15;
    int row = tid >> 1, d0 = (tid & 1) * 64;
    int r = m0 + row;
    const unsigned short* src = osh + row * 136 + d0;
    if (is_t) {
      if (sel == 0) {
        float qs = p.scales[0];
        unsigned short* dst = p.q_txt + ((size_t)h * 512 + r) * 128 + d0;
#pragma unroll
        for (int i = 0; i < 8; ++i) {
          short8 v = *reinterpret_cast<const short8*>(src + i * 8);
          short8 o;
#pragma unroll
          for (int t = 0; t < 8; ++t)
            o[t] = (short)f2bu(b2f((unsigned short)v[t]) * qs);
          *reinterpret_cast<short8*>(dst + i * 8) = o;
        }
      } else {
        unsigned short* dst =
            (sel == 1 ? p.k_cat : p.v_cat) + ((size_t)h * 2560 + r) * 128 + d0;
#pragma unroll
        for (int i = 0; i < 8; ++i)
          *reinterpret_cast<short8*>(dst + i * 8) =
              *reinterpret_cast<const short8*>(src + i * 8);
      }
    } else {
      int s = r - 512;
      if (sel == 2) {
        unsigned short* dst = p.v_cat + ((size_t)h * 2560 + r) * 128 + d0;
#pragma unroll
        for (int i = 0; i < 8; ++i)
          *reinterpret_cast<short8*>(dst + i * 8) =
              *reinterpret_cast<const short8*>(src + i * 8);
      } else {
        float mv = p.modb[h * 2048 + s];
        float qs = (sel == 0) ? p.scales[1] * mv : mv;
        const float2* rp = reinterpret_cast<const float2*>(p.rope + (size_t)s * 128 + d0);
        unsigned short* dst = (sel == 0)
            ? p.q_img + ((size_t)h * 2048 + s) * 128 + d0
            : p.k_cat + ((size_t)h * 2560 + r) * 128 + d0;
#pragma unroll
        for (int i = 0; i < 8; ++i) {
          short8 v = *reinterpret_cast<const short8*>(src + i * 8);
          short8 o;
#pragma unroll
          for (int t = 0; t < 4; ++t) {
            float2 cs = rp[i * 4 + t];
            float e = b2f((unsigned short)v[2 * t]);
            float od = b2f((unsigned short)v[2 * t + 1]);
            o[2 * t] = (short)f2bu((e * cs.x - od * cs.y) * qs);
            o[2 * t + 1] = (short)f2bu((od * cs.x + e * cs.y) * qs);
          }
          *reinterpret_cast<short8*>(dst + i * 8) = o;
        }
      }
    }
  }
}

// ---------------- flash attention (QBLK=64, NO kv-split, phase-pipelined) -----------
// grid (40, 16): 640 blocks, all co-resident (4 blk/CU x 256 CU = 1024 slots).
// Each block walks all 40 KV tiles; O normalized in-kernel, written once (no merge).
// XCD bijection: each XCD owns 2 heads x 40 q-blocks (K/V ~2.5MB fits its L2).
__global__ __launch_bounds__(256, 4) void attn_kernel(
    const unsigned short* __restrict__ q_txt, const unsigned short* __restrict__ q_img,
    const unsigned short* __restrict__ Kc, const unsigned short* __restrict__ Vt,
    unsigned short* __restrict__ ao) {
  __shared__ __align__(16) char RAW[40960];
  int4* sK = reinterpret_cast<int4*>(RAW);            // [64 kv][16 int4] 16KB
  int4* sV = reinterpret_cast<int4*>(RAW + 16384);    // [128 d][8 int4] 16KB
  int4* sP = reinterpret_cast<int4*>(RAW + 32768);    // [64 q][8 int4] 8KB
  unsigned short* osh = reinterpret_cast<unsigned short*>(RAW);  // overlay, stride 136
  const int tid = threadIdx.x, w = tid >> 6, l = tid & 63, lr = l & 15, lg = l >> 4;
  int flat = blockIdx.x + 40 * blockIdx.y;  // [0,640)
  int sw = (flat & 7) * 80 + (flat >> 3);   // bijective: 640 = 8*80
  const int bx = sw % 40;
  const int h = sw / 40;
  const bool is_t = bx < 8;
  const int orow = is_t ? bx * 64 : 512 + (bx - 8) * 64;
  const unsigned short* Qp = is_t ? q_txt + ((size_t)h * 512 + bx * 64) * 128
                                  : q_img + ((size_t)h * 2048 + (bx - 8) * 64) * 128;
  short8 aq[4];
#pragma unroll
  for (int ds = 0; ds < 4; ++ds) {
    int row = w * 16 + lr;
    aq[ds] = *reinterpret_cast<const short8*>(Qp + (size_t)row * 128 + ds * 32 + lg * 8);
  }
  const int4* Kg = reinterpret_cast<const int4*>(Kc + (size_t)h * 2560 * 128);
  const int4* Vg = reinterpret_cast<const int4*>(Vt + (size_t)h * 128 * 2560);
  const short8* pK = reinterpret_cast<const short8*>(sK);
  const short8* pV = reinterpret_cast<const short8*>(sV);
  const short8* pP = reinterpret_cast<const short8*>(sP);
  unsigned short* sPb = reinterpret_cast<unsigned short*>(sP);
  int krow[4], kch[4], vrow[4], vch[4];
#pragma unroll
  for (int i = 0; i < 4; ++i) {
    int s = i * 256 + tid;
    krow[i] = s >> 4; kch[i] = (s & 15) ^ (krow[i] & 7);
    vrow[i] = s >> 3; vch[i] = (s & 7) ^ (vrow[i] & 7);
  }
  short8 ones8;
#pragma unroll
  for (int i = 0; i < 8; ++i) ones8[i] = (short)0x3F80;

  f32x4 oacc[8] = {};
  f32x4 oacc_l = {};
  float m_run[4];
#pragma unroll
  for (int j = 0; j < 4; ++j) m_run[j] = -1e30f;

  const int kbeg = 0, kend = 40;
#pragma unroll
  for (int i = 0; i < 4; ++i)
    gload16(&Kg[(size_t)(kbeg * 64 + krow[i]) * 16 + kch[i]], &sK[i * 256 + w * 64]);
#pragma unroll
  for (int i = 0; i < 4; ++i)
    gload16(&Vg[(size_t)vrow[i] * 320 + kbeg * 8 + vch[i]], &sV[i * 256 + w * 64]);

  for (int kt = kbeg; kt < kend; ++kt) {
    asm volatile("s_waitcnt vmcnt(4)" ::: "memory");
    __builtin_amdgcn_sched_barrier(0);
    __builtin_amdgcn_s_barrier();
    f32x4 sacc[4] = {};
    __builtin_amdgcn_s_setprio(1);
#pragma unroll
    for (int ds = 0; ds < 4; ++ds) {
      short8 bk[4];
#pragma unroll
      for (int n = 0; n < 4; ++n) {
        int row = n * 16 + lr;
        bk[n] = pK[row * 16 + ((ds * 4 + lg) ^ (row & 7))];
      }
#pragma unroll
      for (int n = 0; n < 4; ++n)
        sacc[n] = __builtin_amdgcn_mfma_f32_16x16x32_bf16(aq[ds], bk[n], sacc[n], 0, 0, 0);
    }
    __builtin_amdgcn_s_setprio(0);
    __builtin_amdgcn_s_barrier();  // release sK
    if (kt + 1 < kend) {
#pragma unroll
      for (int i = 0; i < 4; ++i)
        gload16(&Kg[(size_t)((kt + 1) * 64 + krow[i]) * 16 + kch[i]], &sK[i * 256 + w * 64]);
    }
    float corr_[4];
    bool grow_any = false;
#pragma unroll
    for (int j = 0; j < 4; ++j) {
      float mx = fmaxf(fmaxf(sacc[0][j], sacc[1][j]), fmaxf(sacc[2][j], sacc[3][j]));
      mx = fmaxf(mx, __shfl_xor(mx, 1));
      mx = fmaxf(mx, __shfl_xor(mx, 2));
      mx = fmaxf(mx, __shfl_xor(mx, 4));
      mx = fmaxf(mx, __shfl_xor(mx, 8));
      bool grow = mx > m_run[j] + 11.0f;
      grow_any |= grow;
      float mn = grow ? mx : m_run[j];
      corr_[j] = grow ? exp2f(m_run[j] - mn) : 1.0f;
      m_run[j] = mn;
      int prow = w * 16 + lg * 4 + j;
#pragma unroll
      for (int n = 0; n < 4; ++n) {
        float pp = exp2f(sacc[n][j] - mn);
        int col = n * 16 + lr;
        sPb[prow * 64 + (((col >> 3) ^ (prow & 7)) << 3) + (col & 7)] = f2bt(pp);
      }
    }
    if (__any(grow_any)) {
#pragma unroll
      for (int n = 0; n < 8; ++n)
#pragma unroll
        for (int j = 0; j < 4; ++j) oacc[n][j] *= corr_[j];
#pragma unroll
      for (int j = 0; j < 4; ++j) oacc_l[j] *= corr_[j];
    }
    if (kt + 1 < kend) {
      asm volatile("s_waitcnt vmcnt(4)" ::: "memory");
    } else {
      asm volatile("s_waitcnt vmcnt(0)" ::: "memory");
    }
    __builtin_amdgcn_sched_barrier(0);
    __builtin_amdgcn_s_barrier();
    __builtin_amdgcn_s_setprio(1);
#pragma unroll
    for (int kk = 0; kk < 2; ++kk) {
      short8 ap, bv[8];
      {
        int row = w * 16 + lr;
        ap = pP[row * 8 + ((kk * 4 + lg) ^ (row & 7))];
      }
#pragma unroll
      for (int n = 0; n < 8; ++n) {
        int row = n * 16 + lr;
        bv[n] = pV[row * 8 + ((kk * 4 + lg) ^ (row & 7))];
      }
#pragma unroll
      for (int n = 0; n < 8; ++n)
        oacc[n] = __builtin_amdgcn_mfma_f32_16x16x32_bf16(ap, bv[n], oacc[n], 0, 0, 0);
      oacc_l = __builtin_amdgcn_mfma_f32_16x16x32_bf16(ap, ones8, oacc_l, 0, 0, 0);
    }
    __builtin_amdgcn_s_setprio(0);
    __builtin_amdgcn_s_barrier();  // release sV
    if (kt + 1 < kend) {
#pragma unroll
      for (int i = 0; i < 4; ++i)
        gload16(&Vg[(size_t)vrow[i] * 320 + (kt + 1) * 8 + vch[i]], &sV[i * 256 + w * 64]);
    }
  }
  // finalize: normalize by l, stage to LDS, coalesced bf16 store (no merge pass)
  __syncthreads();  // sK/sV/sP dead -> osh overlay
#pragma unroll
  for (int j = 0; j < 4; ++j) {
    int row = w * 16 + lg * 4 + j;
    float inv = 1.f / oacc_l[j];
#pragma unroll
    for (int n = 0; n < 8; ++n)
      osh[row * 136 + n * 16 + lr] = f2bu(oacc[n][j] * inv);
  }
  __syncthreads();
  {
    int row = tid >> 2, c0 = (tid & 3) * 32;
#pragma unroll
    for (int i = 0; i < 4; ++i)
      *reinterpret_cast<short8*>(ao + (size_t)(orow + row) * 2048 + h * 128 + c0 + i * 8) =
          *reinterpret_cast<const short8*>(osh + row * 136 + c0 + i * 8);
  }
}

extern "C" void kernel_launch(void* const* d_in, const int* in_sizes, int n_in,
                              void* d_out, int out_size, void* d_ws, size_t ws_size,
                              hipStream_t stream) {
  (void)in_sizes; (void)n_in; (void)out_size; (void)ws_size;
  const float* txt = (const float*)d_in[0];
  const float* img = (const float*)d_in[1];
  const float* vec = (const float*)d_in[2];
  const float* rope = (const float*)d_in[3];
  const float* sol_t = (const float*)d_in[4];
  const float* sol_s = (const float*)d_in[5];
  const float* ada_img_w = (const float*)d_in[6];
  const float* ada_img_b = (const float*)d_in[7];
  const float* ada_img_nw = (const float*)d_in[8];
  const float* ada_txt_w = (const float*)d_in[9];
  const float* ada_txt_b = (const float*)d_in[10];
  const float* ada_txt_nw = (const float*)d_in[11];
  const float* txt_qkv_w = (const float*)d_in[12];
  const float* img_qkv_w = (const float*)d_in[13];
  const float* txt_out_w = (const float*)d_in[14];
  const float* img_out_w = (const float*)d_in[15];
  const float* mod_w = (const float*)d_in[16];
  const float* mod_b = (const float*)d_in[17];
  const float* img_n2_w = (const float*)d_in[18];
  const float* txt_n2_w = (const float*)d_in[19];
  const float* img_fc1_w = (const float*)d_in[20];
  const float* img_fc1_b = (const float*)d_in[21];
  const float* img_fc2_w = (const float*)d_in[22];
  const float* img_fc2_b = (const float*)d_in[23];
  const float* txt_fc1_w = (const float*)d_in[24];
  const float* txt_fc1_b = (const float*)d_in[25];
  const float* txt_fc2_w = (const float*)d_in[26];
  const float* txt_fc2_b = (const float*)d_in[27];
  float* out = (float*)d_out;
  char* ws = (char*)d_ws;

  const size_t MB = 1 << 20;
  float* silu_vec = (float*)(ws + 0);
  float* scales = (float*)(ws + 8192);
  float* modb = (float*)(ws + 16384);
  float* e_img = (float*)(ws + 147456);
  float* e_txt = (float*)(ws + 196608);
  unsigned short* wt0 = (unsigned short*)(ws + 1 * MB);    // 32MB txt weights
  unsigned short* wt1 = (unsigned short*)(ws + 33 * MB);   // 32MB img weights
  unsigned short* actA = (unsigned short*)(ws + 65 * MB);  // [2560][2048] bf16, 10MB
  char* attn_base = ws + 75 * MB;                          // 50MB region
  unsigned short* q_txt = (unsigned short*)(attn_base);
  unsigned short* q_img = (unsigned short*)(attn_base + 2 * MB);
  unsigned short* k_cat = (unsigned short*)(attn_base + 10 * MB);
  unsigned short* v_cat = (unsigned short*)(attn_base + 20 * MB);
  unsigned short* vT = (unsigned short*)(attn_base + 30 * MB);
  unsigned short* ao = (unsigned short*)(attn_base + 40 * MB);
  unsigned short* actB = (unsigned short*)attn_base;  // [2560][8192] bf16 (MLP phase)
  float* Cbuf = (float*)(ws + 125 * MB);  // [2560][2048] f32 = 20MB

  prep_small<<<1, 256, 0, stream>>>(vec, sol_t, silu_vec, scales);
  mod_kernel<<<128, 256, 0, stream>>>(sol_s, mod_w, mod_b, modb);
  ada_gemv<<<dim3(192, 2), 256, 0, stream>>>(silu_vec, ada_img_w, ada_img_b,
                                             ada_txt_w, ada_txt_b, e_img, e_txt);
  norm1_kernel<<<2560, 256, 0, stream>>>(txt, img, ada_txt_nw, ada_img_nw,
                                         e_txt, e_img, actA);
  transpose_w2<<<dim3(96, 32, 2), 256, 0, stream>>>(txt_qkv_w, img_qkv_w,
                                                    wt0, wt1, 2048, 6144);
  {
    GemmP p = {actA, wt0, wt1, nullptr, nullptr, nullptr, nullptr,
               rope, modb, q_txt, q_img, k_cat, v_cat, scales,
               nullptr, nullptr, 4, 6144, 2048, 1};
    gemm2<2><<<dim3(48, 20, 1), 256, 0, stream>>>(p);
  }
  transpose_v<<<dim3(80, 4, 16), dim3(32, 8), 0, stream>>>(v_cat, vT);
  attn_kernel<<<dim3(40, 16), 256, 0, stream>>>(q_txt, q_img, k_cat, vT, ao);
  transpose_w2<<<dim3(32, 32, 2), 256, 0, stream>>>(txt_out_w, img_out_w,
                                                    wt0, wt1, 2048, 2048);
  {
    // out-projection, single-K (320 blocks, all co-resident)
    GemmP p = {ao, wt0, wt1, Cbuf, nullptr, nullptr, nullptr,
               nullptr, nullptr, nullptr, nullptr, nullptr, nullptr, nullptr,
               nullptr, nullptr, 4, 2048, 2048, 1};
    gemm2<0><<<dim3(16, 20, 1), 256, 0, stream>>>(p);
  }
  res1_rms<<<2560, 256, 0, stream>>>(txt, img, Cbuf, e_txt, e_img,
                                     txt_n2_w, img_n2_w, out, actA);
  transpose_w2<<<dim3(128, 32, 2), 256, 0, stream>>>(txt_fc1_w, img_fc1_w,
                                                     wt0, wt1, 2048, 8192);
  {
    GemmP p = {actA, wt0, wt1, nullptr, actB, txt_fc1_b, img_fc1_b,
               nullptr, nullptr, nullptr, nullptr, nullptr, nullptr, nullptr,
               nullptr, nullptr, 4, 8192, 2048, 1};
    gemm2<1><<<dim3(64, 20, 1), 256, 0, stream>>>(p);
  }
  transpose_w2<<<dim3(32, 128, 2), 256, 0, stream>>>(txt_fc2_w, img_fc2_w,
                                                     wt0, wt1, 8192, 2048);
  {
    // fc2, single-K, fused residual2 epilogue (out += g*(C+bias))
    GemmP p = {actB, wt0, wt1, out, nullptr, txt_fc2_b, img_fc2_b,
               nullptr, nullptr, nullptr, nullptr, nullptr, nullptr, nullptr,
               e_txt, e_img, 4, 2048, 8192, 1};
    gemm2<3><<<dim3(16, 20, 1), 256, 0, stream>>>(p);
  }
}

// Round 22
// 687.182 us; speedup vs baseline: 1.0405x; 1.0050x over previous
//
#include <hip/hip_runtime.h>

typedef short short8 __attribute__((ext_vector_type(8)));
typedef float f32x4 __attribute__((ext_vector_type(4)));

__device__ __forceinline__ unsigned short f2bu(float f) {
  unsigned u = __builtin_bit_cast(unsigned, f);
  u += 0x7fffu + ((u >> 16) & 1u);
  return (unsigned short)(u >> 16);
}

// truncating bf16 pack (1 VALU op) — for paths where bias cancels (softmax P / O)
__device__ __forceinline__ unsigned short f2bt(float f) {
  return (unsigned short)(__builtin_bit_cast(unsigned, f) >> 16);
}

__device__ __forceinline__ float b2f(unsigned short b) {
  unsigned u = (unsigned)b << 16;
  return __builtin_bit_cast(float, u);
}

__device__ __forceinline__ float gelu_t(float x) {
  float x3 = x * x * x;
  float t = tanhf(0.7978845608028654f * (x + 0.044715f * x3));
  return 0.5f * x * (1.f + t);
}

__device__ __forceinline__ void gload16(const void* g, void* l) {
  __builtin_amdgcn_global_load_lds(
      (const __attribute__((address_space(1))) void*)g,
      (__attribute__((address_space(3))) void*)l, 16, 0, 0);
}

// ---------------- small prep ----------------
__global__ __launch_bounds__(256) void prep_small(
    const float* __restrict__ vec, const float* __restrict__ sol_t,
    float* __restrict__ silu_vec, float* __restrict__ scales) {
  __shared__ float red[4];
  int t = threadIdx.x;
  float v = (t < 64) ? sol_t[t] : 0.f;
#pragma unroll
  for (int o = 32; o > 0; o >>= 1) v += __shfl_down(v, o);
  if ((t & 63) == 0) red[t >> 6] = v;
  __syncthreads();
  if (t == 0) {
    float m = (red[0] + red[1] + red[2] + red[3]) * (1.f / 64.f);
    m = fmaxf(m, 0.1f);
    const float sc = 0.08838834764831845f;   // 128^-0.5
    const float l2e = 1.4426950408889634f;   // scores computed in log2 domain
    scales[0] = sc * l2e;
    scales[1] = sc / m * l2e;
  }
  for (int k = t; k < 2048; k += 256) {
    float x = vec[k];
    silu_vec[k] = x / (1.f + expf(-x));
  }
}

__global__ __launch_bounds__(256) void mod_kernel(
    const float* __restrict__ S, const float* __restrict__ mw,
    const float* __restrict__ mb, float* __restrict__ modb) {
  int idx = blockIdx.x * 256 + threadIdx.x;  // 16*2048
  int h = idx >> 11, n = idx & 2047;
  int y = n >> 5, x = n & 31;
  float cy = (y + 0.5f) * 0.125f - 0.5f;
  float cx = (x + 0.5f) * 0.25f - 0.5f;
  int y0 = (int)floorf(cy); float fy = cy - (float)y0;
  int x0 = (int)floorf(cx); float fx = cx - (float)x0;
  int y0c = min(max(y0, 0), 7), y1c = min(max(y0 + 1, 0), 7);
  int x0c = min(max(x0, 0), 7), x1c = min(max(x0 + 1, 0), 7);
  float v = (1.f - fy) * ((1.f - fx) * S[y0c * 8 + x0c] + fx * S[y0c * 8 + x1c]) +
            fy * ((1.f - fx) * S[y1c * 8 + x0c] + fx * S[y1c * 8 + x1c]);
  float t = v * mw[h] + mb[h];
  t = fminf(fmaxf(t, -2.f), 2.f);
  modb[idx] = expf(t);
}

__global__ __launch_bounds__(256) void ada_gemv(
    const float* __restrict__ sv,
    const float* __restrict__ Wi, const float* __restrict__ bi,
    const float* __restrict__ Wt, const float* __restrict__ bt,
    float* __restrict__ ei, float* __restrict__ et) {
  __shared__ float red[4][64];
  const float* W = blockIdx.y ? Wt : Wi;
  const float* bb = blockIdx.y ? bt : bi;
  float* e = blockIdx.y ? et : ei;
  int jl = threadIdx.x & 63, ks = threadIdx.x >> 6;
  int j = blockIdx.x * 64 + jl;
  float acc = 0.f;
  int k0 = ks * 512;
#pragma unroll 4
  for (int k = 0; k < 512; ++k) acc += sv[k0 + k] * W[(size_t)(k0 + k) * 12288 + j];
  red[ks][jl] = acc;
  __syncthreads();
  if (ks == 0) e[j] = red[0][jl] + red[1][jl] + red[2][jl] + red[3][jl] + bb[j];
}

// ---------------- norm1: RMSNorm + adaLN modulate (txt+img merged) -> bf16 ----------
__global__ __launch_bounds__(256) void norm1_kernel(
    const float* __restrict__ txt, const float* __restrict__ img,
    const float* __restrict__ nw_t, const float* __restrict__ nw_i,
    const float* __restrict__ e_t, const float* __restrict__ e_i,
    unsigned short* __restrict__ out) {
  __shared__ float red[4];
  int r = blockIdx.x, t = threadIdx.x;
  bool ist = r < 512;
  const float* X = ist ? txt + (size_t)r * 2048 : img + (size_t)(r - 512) * 2048;
  const float* nw = ist ? nw_t : nw_i;
  const float* e = ist ? e_t : e_i;
  const float4* xr = reinterpret_cast<const float4*>(X);
  float4 v0 = xr[t * 2], v1 = xr[t * 2 + 1];
  float ss = v0.x * v0.x + v0.y * v0.y + v0.z * v0.z + v0.w * v0.w +
             v1.x * v1.x + v1.y * v1.y + v1.z * v1.z + v1.w * v1.w;
#pragma unroll
  for (int o = 32; o > 0; o >>= 1) ss += __shfl_down(ss, o);
  if ((t & 63) == 0) red[t >> 6] = ss;
  __syncthreads();
  float rinv = rsqrtf((red[0] + red[1] + red[2] + red[3]) * (1.f / 2048.f) + 1e-6f);
  int c0 = t * 8;
  float xv[8] = {v0.x, v0.y, v0.z, v0.w, v1.x, v1.y, v1.z, v1.w};
  short8 ov;
#pragma unroll
  for (int i = 0; i < 8; ++i) {
    int c = c0 + i;
    float y = xv[i] * rinv * nw[c] * (1.f + e[2048 + c]) + e[c];
    ov[i] = (short)f2bu(y);
  }
  *reinterpret_cast<short8*>(out + (size_t)r * 2048 + c0) = ov;
}

// ---------------- fused residual1 + RMSNorm2+mod (single partial) ----------------
__global__ __launch_bounds__(256) void res1_rms(
    const float* __restrict__ txt, const float* __restrict__ img,
    const float* __restrict__ P0,
    const float* __restrict__ e_t, const float* __restrict__ e_i,
    const float* __restrict__ nw_t, const float* __restrict__ nw_i,
    float* __restrict__ out, unsigned short* __restrict__ actA) {
  __shared__ float red[4];
  int r = blockIdx.x, t = threadIdx.x;
  bool ist = r < 512;
  const float* X = ist ? txt + (size_t)r * 2048 : img + (size_t)(r - 512) * 2048;
  const float* e = ist ? e_t : e_i;
  const float* nw = ist ? nw_t : nw_i;
  int c0 = t * 8;
  const float* p0 = P0 + (size_t)r * 2048 + c0;
  float o[8];
  float ss = 0.f;
#pragma unroll
  for (int i = 0; i < 8; i += 4) {
    float4 x = *reinterpret_cast<const float4*>(X + c0 + i);
    float4 a = *reinterpret_cast<const float4*>(p0 + i);
    float4 g = *reinterpret_cast<const float4*>(e + 4096 + c0 + i);
    o[i + 0] = x.x + g.x * a.x;
    o[i + 1] = x.y + g.y * a.y;
    o[i + 2] = x.z + g.z * a.z;
    o[i + 3] = x.w + g.w * a.w;
    ss += o[i] * o[i] + o[i + 1] * o[i + 1] + o[i + 2] * o[i + 2] + o[i + 3] * o[i + 3];
  }
  *reinterpret_cast<float4*>(out + (size_t)r * 2048 + c0) =
      make_float4(o[0], o[1], o[2], o[3]);
  *reinterpret_cast<float4*>(out + (size_t)r * 2048 + c0 + 4) =
      make_float4(o[4], o[5], o[6], o[7]);
#pragma unroll
  for (int of = 32; of > 0; of >>= 1) ss += __shfl_down(ss, of);
  if ((t & 63) == 0) red[t >> 6] = ss;
  __syncthreads();
  float rinv = rsqrtf((red[0] + red[1] + red[2] + red[3]) * (1.f / 2048.f) + 1e-6f);
  short8 ov;
#pragma unroll
  for (int i = 0; i < 8; ++i) {
    int c = c0 + i;
    float y = o[i] * rinv * nw[c] * (1.f + e[8192 + c]) + e[6144 + c];
    ov[i] = (short)f2bu(y);
  }
  *reinterpret_cast<short8*>(actA + (size_t)r * 2048 + c0) = ov;
}

// ---------------- weight transpose+convert v2: f32 [K][N] -> bf16 [N][K] ------------
__global__ __launch_bounds__(256) void transpose_w2(
    const float* __restrict__ W0, const float* __restrict__ W1,
    unsigned short* __restrict__ B0, unsigned short* __restrict__ B1,
    int K, int N) {
  __shared__ float tile[64][65];
  const float* W = blockIdx.z ? W1 : W0;
  unsigned short* Bt = blockIdx.z ? B1 : B0;
  int n0 = blockIdx.x * 64, k0 = blockIdx.y * 64;
  int t = threadIdx.x;
  int rn = (t & 15) * 4, rk = t >> 4;
#pragma unroll
  for (int j = 0; j < 4; ++j) {
    float4 v = *reinterpret_cast<const float4*>(
        W + (size_t)(k0 + rk + j * 16) * N + n0 + rn);
    tile[rk + j * 16][rn + 0] = v.x;
    tile[rk + j * 16][rn + 1] = v.y;
    tile[rk + j * 16][rn + 2] = v.z;
    tile[rk + j * 16][rn + 3] = v.w;
  }
  __syncthreads();
  int wn = t >> 2, wk = (t & 3) * 16;
  unsigned pk[8];
#pragma unroll
  for (int i = 0; i < 8; ++i) {
    float lo = tile[wk + 2 * i][wn], hi = tile[wk + 2 * i + 1][wn];
    pk[i] = (unsigned)f2bu(lo) | ((unsigned)f2bu(hi) << 16);
  }
  unsigned short* dst = Bt + (size_t)(n0 + wn) * K + k0 + wk;
  *reinterpret_cast<int4*>(dst) = make_int4(pk[0], pk[1], pk[2], pk[3]);
  *reinterpret_cast<int4*>(dst + 8) = make_int4(pk[4], pk[5], pk[6], pk[7]);
}

// ---------------- batched GEMM (txt rows 0..511, img rows 512..2559) ----------------
// EPI 0: f32 store. EPI 1: bf16 gelu(acc+bias). EPI 2: qkv scatter (V -> vT direct).
// EPI 3: fused res2.
struct GemmP {
  const unsigned short *A, *Bt_t, *Bt_i;
  float* C;            // EPI0: partial base; EPI3: 'out' (RMW)
  unsigned short* Cb;
  const float *bias_t, *bias_i;
  const float *rope, *modb;
  unsigned short *q_txt, *q_img, *k_cat, *vT;
  const float* scales;
  const float *ga_t, *ga_i;  // EPI3 gate arrays (e_txt, e_img)
  int Mb_t;
  int N, K, KS;
};

template <int EPI>
__global__ __launch_bounds__(256) void gemm2(GemmP p) {
  __shared__ __align__(16) char GRAW[65536];
  int4* sAb = reinterpret_cast<int4*>(GRAW);            // [2][1024] int4 (32KB)
  int4* sBb = reinterpret_cast<int4*>(GRAW + 32768);    // [2][1024] int4 (32KB)
  const int NB = gridDim.x, MBT = gridDim.y;
  int nwg = NB * MBT;
  int orig = blockIdx.y * NB + blockIdx.x;
  int qq = nwg >> 3, rr = nwg & 7, xcd = orig & 7, base = orig >> 3;
  int sw = (xcd < rr ? xcd * (qq + 1) : rr * (qq + 1) + (xcd - rr) * qq) + base;
  int bx = sw / MBT, by = sw % MBT;
  const bool is_t = by < p.Mb_t;
  const unsigned short* Bt = is_t ? p.Bt_t : p.Bt_i;
  const int m0 = by * 128, n0 = bx * 128;
  const int z = blockIdx.z;
  const int Kz = p.K / p.KS, kbeg = z * Kz, kend = kbeg + Kz;
  const int tid = threadIdx.x;
  const int w = tid >> 6, l = tid & 63, lr = l & 15, lg = l >> 4;
  const int wm = (w >> 1) * 64, wn = (w & 1) * 64;
  f32x4 acc[4][4] = {};
  const int4* Ag = reinterpret_cast<const int4*>(p.A);
  const int4* Bg = reinterpret_cast<const int4*>(Bt);
  const int K8 = p.K >> 3;
  int srow[4], sch[4];
#pragma unroll
  for (int i = 0; i < 4; ++i) {
    int s = i * 256 + tid;
    srow[i] = s >> 3;
    sch[i] = (s & 7) ^ (srow[i] & 7);
  }
  {
    int kc = kbeg >> 3;
#pragma unroll
    for (int i = 0; i < 4; ++i) {
      gload16(&Ag[(size_t)(m0 + srow[i]) * K8 + kc + sch[i]], &sAb[i * 256 + w * 64]);
      gload16(&Bg[(size_t)(n0 + srow[i]) * K8 + kc + sch[i]], &sBb[i * 256 + w * 64]);
    }
  }
  asm volatile("s_waitcnt vmcnt(0)" ::: "memory");
  __builtin_amdgcn_sched_barrier(0);
  __builtin_amdgcn_s_barrier();
  int cur = 0;
  for (int k0 = kbeg; k0 < kend; k0 += 64) {
    if (k0 + 64 < kend) {
      int kc = (k0 + 64) >> 3;
      int nb = (cur ^ 1) * 1024;
#pragma unroll
      for (int i = 0; i < 4; ++i) {
        gload16(&Ag[(size_t)(m0 + srow[i]) * K8 + kc + sch[i]], &sAb[nb + i * 256 + w * 64]);
        gload16(&Bg[(size_t)(n0 + srow[i]) * K8 + kc + sch[i]], &sBb[nb + i * 256 + w * 64]);
      }
      __builtin_amdgcn_sched_barrier(0);
    }
    const short8* pA = reinterpret_cast<const short8*>(sAb + cur * 1024);
    const short8* pB = reinterpret_cast<const short8*>(sBb + cur * 1024);
    __builtin_amdgcn_s_setprio(1);
#pragma unroll
    for (int kk = 0; kk < 2; ++kk) {
      short8 af[4], bf[4];
#pragma unroll
      for (int m = 0; m < 4; ++m) {
        int row = wm + m * 16 + lr;
        af[m] = pA[row * 8 + ((kk * 4 + lg) ^ (row & 7))];
      }
#pragma unroll
      for (int n = 0; n < 4; ++n) {
        int row = wn + n * 16 + lr;
        bf[n] = pB[row * 8 + ((kk * 4 + lg) ^ (row & 7))];
      }
#pragma unroll
      for (int m = 0; m < 4; ++m)
#pragma unroll
        for (int n = 0; n < 4; ++n)
          acc[m][n] = __builtin_amdgcn_mfma_f32_16x16x32_bf16(af[m], bf[n], acc[m][n], 0, 0, 0);
    }
    __builtin_amdgcn_s_setprio(0);
    asm volatile("s_waitcnt vmcnt(0)" ::: "memory");  // next tile landed
    __builtin_amdgcn_sched_barrier(0);
    __builtin_amdgcn_s_barrier();
    cur ^= 1;
  }
  if (EPI == 0) {
    float* C = p.C + (size_t)z * MBT * 128 * p.N;
#pragma unroll
    for (int m = 0; m < 4; ++m)
#pragma unroll
      for (int n = 0; n < 4; ++n)
#pragma unroll
        for (int j = 0; j < 4; ++j) {
          int r = m0 + wm + m * 16 + lg * 4 + j;
          int cc = n0 + wn + n * 16 + lr;
          C[(size_t)r * p.N + cc] = acc[m][n][j];
        }
  } else if (EPI == 1) {
    const float* bias = is_t ? p.bias_t : p.bias_i;
#pragma unroll
    for (int n = 0; n < 4; ++n) {
      int cc = n0 + wn + n * 16 + lr;
      float bv = bias[cc];
#pragma unroll
      for (int m = 0; m < 4; ++m)
#pragma unroll
        for (int j = 0; j < 4; ++j) {
          int r = m0 + wm + m * 16 + lg * 4 + j;
          p.Cb[(size_t)r * p.N + cc] = f2bu(gelu_t(acc[m][n][j] + bv));
        }
    }
  } else if (EPI == 3) {
    // fused residual2: out += g*(acc+bias), staged through LDS bf16, coalesced RMW
    unsigned short* osh = reinterpret_cast<unsigned short*>(GRAW);  // [128][136]
#pragma unroll
    for (int m = 0; m < 4; ++m)
#pragma unroll
      for (int n = 0; n < 4; ++n)
#pragma unroll
        for (int j = 0; j < 4; ++j) {
          int row = wm + m * 16 + lg * 4 + j;
          int col = wn + n * 16 + lr;
          osh[row * 136 + col] = f2bu(acc[m][n][j]);
        }
    __syncthreads();
    const float* gat = (is_t ? p.ga_t : p.ga_i) + 10240;
    const float* bias = is_t ? p.bias_t : p.bias_i;
    int row = tid >> 1, d0 = (tid & 1) * 64;
    int r = m0 + row;
    const unsigned short* src = osh + row * 136 + d0;
    float* op = p.C + (size_t)r * p.N + n0 + d0;
#pragma unroll
    for (int i = 0; i < 16; ++i) {
      float4 o = *reinterpret_cast<const float4*>(op + i * 4);
      float4 g = *reinterpret_cast<const float4*>(gat + n0 + d0 + i * 4);
      float4 bv = *reinterpret_cast<const float4*>(bias + n0 + d0 + i * 4);
      o.x += g.x * (b2f(src[i * 4 + 0]) + bv.x);
      o.y += g.y * (b2f(src[i * 4 + 1]) + bv.y);
      o.z += g.z * (b2f(src[i * 4 + 2]) + bv.z);
      o.w += g.w * (b2f(src[i * 4 + 3]) + bv.w);
      *reinterpret_cast<float4*>(op + i * 4) = o;
    }
  } else {
    unsigned short* osh = reinterpret_cast<unsigned short*>(GRAW);  // [128][136]
#pragma unroll
    for (int m = 0; m < 4; ++m)
#pragma unroll
      for (int n = 0; n < 4; ++n)
#pragma unroll
        for (int j = 0; j < 4; ++j) {
          int row = wm + m * 16 + lg * 4 + j;
          int col = wn + n * 16 + lr;
          osh[row * 136 + col] = f2bu(acc[m][n][j]);
        }
    __syncthreads();
    int sel = bx >> 4, h = bx & 15;
    if (sel == 2) {
      // V: write transposed directly to vT[h][d][r] (kills transpose_v kernel).
      // Thread owns column d = tid>>1, s-half = tid&1: 64 contiguous bf16 out.
      int d = tid >> 1, sh = (tid & 1) * 64;
      unsigned short* dst = p.vT + ((size_t)h * 128 + d) * 2560 + m0 + sh;
#pragma unroll
      for (int i = 0; i < 8; ++i) {
        short8 o;
#pragma unroll
        for (int e = 0; e < 8; ++e)
          o[e] = (short)osh[(sh + i * 8 + e) * 136 + d];
        *reinterpret_cast<short8*>(dst + i * 8) = o;
      }
    } else {
      int row = tid >> 1, d0 = (tid & 1) * 64;
      int r = m0 + row;
      const unsigned short* src = osh + row * 136 + d0;
      if (is_t) {
        if (sel == 0) {
          float qs = p.scales[0];
          unsigned short* dst = p.q_txt + ((size_t)h * 512 + r) * 128 + d0;
#pragma unroll
          for (int i = 0; i < 8; ++i) {
            short8 v = *reinterpret_cast<const short8*>(src + i * 8);
            short8 o;
#pragma unroll
            for (int t = 0; t < 8; ++t)
              o[t] = (short)f2bu(b2f((unsigned short)v[t]) * qs);
            *reinterpret_cast<short8*>(dst + i * 8) = o;
          }
        } else {
          unsigned short* dst = p.k_cat + ((size_t)h * 2560 + r) * 128 + d0;
#pragma unroll
          for (int i = 0; i < 8; ++i)
            *reinterpret_cast<short8*>(dst + i * 8) =
                *reinterpret_cast<const short8*>(src + i * 8);
        }
      } else {
        int s = r - 512;
        float mv = p.modb[h * 2048 + s];
        float qs = (sel == 0) ? p.scales[1] * mv : mv;
        const float2* rp = reinterpret_cast<const float2*>(p.rope + (size_t)s * 128 + d0);
        unsigned short* dst = (sel == 0)
            ? p.q_img + ((size_t)h * 2048 + s) * 128 + d0
            : p.k_cat + ((size_t)h * 2560 + r) * 128 + d0;
#pragma unroll
        for (int i = 0; i < 8; ++i) {
          short8 v = *reinterpret_cast<const short8*>(src + i * 8);
          short8 o;
#pragma unroll
          for (int t = 0; t < 4; ++t) {
            float2 cs = rp[i * 4 + t];
            float e = b2f((unsigned short)v[2 * t]);
            float od = b2f((unsigned short)v[2 * t + 1]);
            o[2 * t] = (short)f2bu((e * cs.x - od * cs.y) * qs);
            o[2 * t + 1] = (short)f2bu((od * cs.x + e * cs.y) * qs);
          }
          *reinterpret_cast<short8*>(dst + i * 8) = o;
        }
      }
    }
  }
}

// ---------------- flash attention (QBLK=64, NO kv-split, phase-pipelined) -----------
__global__ __launch_bounds__(256, 4) void attn_kernel(
    const unsigned short* __restrict__ q_txt, const unsigned short* __restrict__ q_img,
    const unsigned short* __restrict__ Kc, const unsigned short* __restrict__ Vt,
    unsigned short* __restrict__ ao) {
  __shared__ __align__(16) char RAW[40960];
  int4* sK = reinterpret_cast<int4*>(RAW);            // [64 kv][16 int4] 16KB
  int4* sV = reinterpret_cast<int4*>(RAW + 16384);    // [128 d][8 int4] 16KB
  int4* sP = reinterpret_cast<int4*>(RAW + 32768);    // [64 q][8 int4] 8KB
  unsigned short* osh = reinterpret_cast<unsigned short*>(RAW);  // overlay, stride 136
  const int tid = threadIdx.x, w = tid >> 6, l = tid & 63, lr = l & 15, lg = l >> 4;
  int flat = blockIdx.x + 40 * blockIdx.y;  // [0,640)
  int sw = (flat & 7) * 80 + (flat >> 3);   // bijective: 640 = 8*80
  const int bx = sw % 40;
  const int h = sw / 40;
  const bool is_t = bx < 8;
  const int orow = is_t ? bx * 64 : 512 + (bx - 8) * 64;
  const unsigned short* Qp = is_t ? q_txt + ((size_t)h * 512 + bx * 64) * 128
                                  : q_img + ((size_t)h * 2048 + (bx - 8) * 64) * 128;
  short8 aq[4];
#pragma unroll
  for (int ds = 0; ds < 4; ++ds) {
    int row = w * 16 + lr;
    aq[ds] = *reinterpret_cast<const short8*>(Qp + (size_t)row * 128 + ds * 32 + lg * 8);
  }
  const int4* Kg = reinterpret_cast<const int4*>(Kc + (size_t)h * 2560 * 128);
  const int4* Vg = reinterpret_cast<const int4*>(Vt + (size_t)h * 128 * 2560);
  const short8* pK = reinterpret_cast<const short8*>(sK);
  const short8* pV = reinterpret_cast<const short8*>(sV);
  const short8* pP = reinterpret_cast<const short8*>(sP);
  unsigned short* sPb = reinterpret_cast<unsigned short*>(sP);
  int krow[4], kch[4], vrow[4], vch[4];
#pragma unroll
  for (int i = 0; i < 4; ++i) {
    int s = i * 256 + tid;
    krow[i] = s >> 4; kch[i] = (s & 15) ^ (krow[i] & 7);
    vrow[i] = s >> 3; vch[i] = (s & 7) ^ (vrow[i] & 7);
  }
  short8 ones8;
#pragma unroll
  for (int i = 0; i < 8; ++i) ones8[i] = (short)0x3F80;

  f32x4 oacc[8] = {};
  f32x4 oacc_l = {};
  float m_run[4];
#pragma unroll
  for (int j = 0; j < 4; ++j) m_run[j] = -1e30f;

  const int kbeg = 0, kend = 40;
#pragma unroll
  for (int i = 0; i < 4; ++i)
    gload16(&Kg[(size_t)(kbeg * 64 + krow[i]) * 16 + kch[i]], &sK[i * 256 + w * 64]);
#pragma unroll
  for (int i = 0; i < 4; ++i)
    gload16(&Vg[(size_t)vrow[i] * 320 + kbeg * 8 + vch[i]], &sV[i * 256 + w * 64]);

  for (int kt = kbeg; kt < kend; ++kt) {
    asm volatile("s_waitcnt vmcnt(4)" ::: "memory");
    __builtin_amdgcn_sched_barrier(0);
    __builtin_amdgcn_s_barrier();
    f32x4 sacc[4] = {};
    __builtin_amdgcn_s_setprio(1);
#pragma unroll
    for (int ds = 0; ds < 4; ++ds) {
      short8 bk[4];
#pragma unroll
      for (int n = 0; n < 4; ++n) {
        int row = n * 16 + lr;
        bk[n] = pK[row * 16 + ((ds * 4 + lg) ^ (row & 7))];
      }
#pragma unroll
      for (int n = 0; n < 4; ++n)
        sacc[n] = __builtin_amdgcn_mfma_f32_16x16x32_bf16(aq[ds], bk[n], sacc[n], 0, 0, 0);
    }
    __builtin_amdgcn_s_setprio(0);
    __builtin_amdgcn_s_barrier();  // release sK
    if (kt + 1 < kend) {
#pragma unroll
      for (int i = 0; i < 4; ++i)
        gload16(&Kg[(size_t)((kt + 1) * 64 + krow[i]) * 16 + kch[i]], &sK[i * 256 + w * 64]);
    }
    float corr_[4];
    bool grow_any = false;
#pragma unroll
    for (int j = 0; j < 4; ++j) {
      float mx = fmaxf(fmaxf(sacc[0][j], sacc[1][j]), fmaxf(sacc[2][j], sacc[3][j]));
      mx = fmaxf(mx, __shfl_xor(mx, 1));
      mx = fmaxf(mx, __shfl_xor(mx, 2));
      mx = fmaxf(mx, __shfl_xor(mx, 4));
      mx = fmaxf(mx, __shfl_xor(mx, 8));
      bool grow = mx > m_run[j] + 11.0f;
      grow_any |= grow;
      float mn = grow ? mx : m_run[j];
      corr_[j] = grow ? exp2f(m_run[j] - mn) : 1.0f;
      m_run[j] = mn;
      int prow = w * 16 + lg * 4 + j;
#pragma unroll
      for (int n = 0; n < 4; ++n) {
        float pp = exp2f(sacc[n][j] - mn);
        int col = n * 16 + lr;
        sPb[prow * 64 + (((col >> 3) ^ (prow & 7)) << 3) + (col & 7)] = f2bt(pp);
      }
    }
    if (__any(grow_any)) {
#pragma unroll
      for (int n = 0; n < 8; ++n)
#pragma unroll
        for (int j = 0; j < 4; ++j) oacc[n][j] *= corr_[j];
#pragma unroll
      for (int j = 0; j < 4; ++j) oacc_l[j] *= corr_[j];
    }
    if (kt + 1 < kend) {
      asm volatile("s_waitcnt vmcnt(4)" ::: "memory");
    } else {
      asm volatile("s_waitcnt vmcnt(0)" ::: "memory");
    }
    __builtin_amdgcn_sched_barrier(0);
    __builtin_amdgcn_s_barrier();
    __builtin_amdgcn_s_setprio(1);
#pragma unroll
    for (int kk = 0; kk < 2; ++kk) {
      short8 ap, bv[8];
      {
        int row = w * 16 + lr;
        ap = pP[row * 8 + ((kk * 4 + lg) ^ (row & 7))];
      }
#pragma unroll
      for (int n = 0; n < 8; ++n) {
        int row = n * 16 + lr;
        bv[n] = pV[row * 8 + ((kk * 4 + lg) ^ (row & 7))];
      }
#pragma unroll
      for (int n = 0; n < 8; ++n)
        oacc[n] = __builtin_amdgcn_mfma_f32_16x16x32_bf16(ap, bv[n], oacc[n], 0, 0, 0);
      oacc_l = __builtin_amdgcn_mfma_f32_16x16x32_bf16(ap, ones8, oacc_l, 0, 0, 0);
    }
    __builtin_amdgcn_s_setprio(0);
    __builtin_amdgcn_s_barrier();  // release sV
    if (kt + 1 < kend) {
#pragma unroll
      for (int i = 0; i < 4; ++i)
        gload16(&Vg[(size_t)vrow[i] * 320 + (kt + 1) * 8 + vch[i]], &sV[i * 256 + w * 64]);
    }
  }
  // finalize: normalize by l, stage to LDS, coalesced bf16 store (no merge pass)
  __syncthreads();  // sK/sV/sP dead -> osh overlay
#pragma unroll
  for (int j = 0; j < 4; ++j) {
    int row = w * 16 + lg * 4 + j;
    float inv = 1.f / oacc_l[j];
#pragma unroll
    for (int n = 0; n < 8; ++n)
      osh[row * 136 + n * 16 + lr] = f2bu(oacc[n][j] * inv);
  }
  __syncthreads();
  {
    int row = tid >> 2, c0 = (tid & 3) * 32;
#pragma unroll
    for (int i = 0; i < 4; ++i)
      *reinterpret_cast<short8*>(ao + (size_t)(orow + row) * 2048 + h * 128 + c0 + i * 8) =
          *reinterpret_cast<const short8*>(osh + row * 136 + c0 + i * 8);
  }
}

extern "C" void kernel_launch(void* const* d_in, const int* in_sizes, int n_in,
                              void* d_out, int out_size, void* d_ws, size_t ws_size,
                              hipStream_t stream) {
  (void)in_sizes; (void)n_in; (void)out_size; (void)ws_size;
  const float* txt = (const float*)d_in[0];
  const float* img = (const float*)d_in[1];
  const float* vec = (const float*)d_in[2];
  const float* rope = (const float*)d_in[3];
  const float* sol_t = (const float*)d_in[4];
  const float* sol_s = (const float*)d_in[5];
  const float* ada_img_w = (const float*)d_in[6];
  const float* ada_img_b = (const float*)d_in[7];
  const float* ada_img_nw = (const float*)d_in[8];
  const float* ada_txt_w = (const float*)d_in[9];
  const float* ada_txt_b = (const float*)d_in[10];
  const float* ada_txt_nw = (const float*)d_in[11];
  const float* txt_qkv_w = (const float*)d_in[12];
  const float* img_qkv_w = (const float*)d_in[13];
  const float* txt_out_w = (const float*)d_in[14];
  const float* img_out_w = (const float*)d_in[15];
  const float* mod_w = (const float*)d_in[16];
  const float* mod_b = (const float*)d_in[17];
  const float* img_n2_w = (const float*)d_in[18];
  const float* txt_n2_w = (const float*)d_in[19];
  const float* img_fc1_w = (const float*)d_in[20];
  const float* img_fc1_b = (const float*)d_in[21];
  const float* img_fc2_w = (const float*)d_in[22];
  const float* img_fc2_b = (const float*)d_in[23];
  const float* txt_fc1_w = (const float*)d_in[24];
  const float* txt_fc1_b = (const float*)d_in[25];
  const float* txt_fc2_w = (const float*)d_in[26];
  const float* txt_fc2_b = (const float*)d_in[27];
  float* out = (float*)d_out;
  char* ws = (char*)d_ws;

  const size_t MB = 1 << 20;
  float* silu_vec = (float*)(ws + 0);
  float* scales = (float*)(ws + 8192);
  float* modb = (float*)(ws + 16384);
  float* e_img = (float*)(ws + 147456);
  float* e_txt = (float*)(ws + 196608);
  unsigned short* wt0 = (unsigned short*)(ws + 1 * MB);    // 32MB txt weights
  unsigned short* wt1 = (unsigned short*)(ws + 33 * MB);   // 32MB img weights
  unsigned short* actA = (unsigned short*)(ws + 65 * MB);  // [2560][2048] bf16, 10MB
  char* attn_base = ws + 75 * MB;                          // 50MB region
  unsigned short* q_txt = (unsigned short*)(attn_base);
  unsigned short* q_img = (unsigned short*)(attn_base + 2 * MB);
  unsigned short* k_cat = (unsigned short*)(attn_base + 10 * MB);
  unsigned short* vT = (unsigned short*)(attn_base + 20 * MB);
  unsigned short* ao = (unsigned short*)(attn_base + 40 * MB);
  unsigned short* actB = (unsigned short*)attn_base;  // [2560][8192] bf16 (MLP phase)
  float* Cbuf = (float*)(ws + 125 * MB);  // [2560][2048] f32 = 20MB

  prep_small<<<1, 256, 0, stream>>>(vec, sol_t, silu_vec, scales);
  mod_kernel<<<128, 256, 0, stream>>>(sol_s, mod_w, mod_b, modb);
  ada_gemv<<<dim3(192, 2), 256, 0, stream>>>(silu_vec, ada_img_w, ada_img_b,
                                             ada_txt_w, ada_txt_b, e_img, e_txt);
  norm1_kernel<<<2560, 256, 0, stream>>>(txt, img, ada_txt_nw, ada_img_nw,
                                         e_txt, e_img, actA);
  transpose_w2<<<dim3(96, 32, 2), 256, 0, stream>>>(txt_qkv_w, img_qkv_w,
                                                    wt0, wt1, 2048, 6144);
  {
    GemmP p = {actA, wt0, wt1, nullptr, nullptr, nullptr, nullptr,
               rope, modb, q_txt, q_img, k_cat, vT, scales,
               nullptr, nullptr, 4, 6144, 2048, 1};
    gemm2<2><<<dim3(48, 20, 1), 256, 0, stream>>>(p);
  }
  attn_kernel<<<dim3(40, 16), 256, 0, stream>>>(q_txt, q_img, k_cat, vT, ao);
  transpose_w2<<<dim3(32, 32, 2), 256, 0, stream>>>(txt_out_w, img_out_w,
                                                    wt0, wt1, 2048, 2048);
  {
    // out-projection, single-K (320 blocks, all co-resident)
    GemmP p = {ao, wt0, wt1, Cbuf, nullptr, nullptr, nullptr,
               nullptr, nullptr, nullptr, nullptr, nullptr, nullptr, nullptr,
               nullptr, nullptr, 4, 2048, 2048, 1};
    gemm2<0><<<dim3(16, 20, 1), 256, 0, stream>>>(p);
  }
  res1_rms<<<2560, 256, 0, stream>>>(txt, img, Cbuf, e_txt, e_img,
                                     txt_n2_w, img_n2_w, out, actA);
  transpose_w2<<<dim3(128, 32, 2), 256, 0, stream>>>(txt_fc1_w, img_fc1_w,
                                                     wt0, wt1, 2048, 8192);
  {
    GemmP p = {actA, wt0, wt1, nullptr, actB, txt_fc1_b, img_fc1_b,
               nullptr, nullptr, nullptr, nullptr, nullptr, nullptr, nullptr,
               nullptr, nullptr, 4, 8192, 2048, 1};
    gemm2<1><<<dim3(64, 20, 1), 256, 0, stream>>>(p);
  }
  transpose_w2<<<dim3(32, 128, 2), 256, 0, stream>>>(txt_fc2_w, img_fc2_w,
                                                     wt0, wt1, 8192, 2048);
  {
    // fc2, single-K, fused residual2 epilogue (out += g*(C+bias))
    GemmP p = {actB, wt0, wt1, out, nullptr, txt_fc2_b, img_fc2_b,
               nullptr, nullptr, nullptr, nullptr, nullptr, nullptr, nullptr,
               e_txt, e_img, 4, 2048, 8192, 1};
    gemm2<3><<<dim3(16, 20, 1), 256, 0, stream>>>(p);
  }
}